// Round 1
// baseline (1002.817 us; speedup 1.0000x reference)
//
#include <hip/hip_runtime.h>
#include <hip/hip_bf16.h>

// Problem dims (fixed by setup_inputs): B=2, S=2048, D=1024, F=4096, T=8
#define N_ROWS 4096   // B*S
#define DDIM   1024
#define FDIM   4096

constexpr int BM = 128, BN = 128, BK = 8;

static __device__ __forceinline__ float bf16bits_to_f32(unsigned short u) {
    return __uint_as_float(((unsigned)u) << 16);
}

// Kernel 1: h = x @ w_up^T (fp32), fused T-step LIF recurrence -> rate (bf16) to ws.
__global__ __launch_bounds__(256) void up_spike_kernel(
    const float* __restrict__ x, const float* __restrict__ wup,
    const float* __restrict__ beta, const int* __restrict__ Tp,
    __hip_bfloat16* __restrict__ rate)
{
    __shared__ float As[BK][BM];
    __shared__ float Bs[BK][BN];
    const int bm = blockIdx.y * BM;          // row tile (n)
    const int bn = blockIdx.x * BN;          // col tile (f)
    const int t  = threadIdx.x;
    const int tx = t & 15, ty = t >> 4;      // 16x16 thread grid, 8x8 micro-tile
    const int lr = t >> 1;                   // 0..127 load row
    const int lc = (t & 1) * 4;              // 0 or 4 load col
    const float* Ap = x   + (size_t)(bm + lr) * DDIM + lc;
    const float* Bp = wup + (size_t)(bn + lr) * DDIM + lc;

    float acc[8][8] = {};
    for (int k0 = 0; k0 < DDIM; k0 += BK) {
        float4 a = *(const float4*)(Ap + k0);
        float4 b = *(const float4*)(Bp + k0);
        __syncthreads();
        As[lc+0][lr] = a.x; As[lc+1][lr] = a.y; As[lc+2][lr] = a.z; As[lc+3][lr] = a.w;
        Bs[lc+0][lr] = b.x; Bs[lc+1][lr] = b.y; Bs[lc+2][lr] = b.z; Bs[lc+3][lr] = b.w;
        __syncthreads();
#pragma unroll
        for (int k = 0; k < BK; ++k) {
            float av[8], bv[8];
            *(float4*)&av[0] = *(const float4*)&As[k][ty*8];
            *(float4*)&av[4] = *(const float4*)&As[k][ty*8+4];
            *(float4*)&bv[0] = *(const float4*)&Bs[k][tx*8];
            *(float4*)&bv[4] = *(const float4*)&Bs[k][tx*8+4];
#pragma unroll
            for (int i = 0; i < 8; ++i)
#pragma unroll
                for (int j = 0; j < 8; ++j)
                    acc[i][j] = fmaf(av[i], bv[j], acc[i][j]);
        }
    }

    const int T = Tp[0];
    const float invT = 1.0f / (float)T;
    float betav[8];
#pragma unroll
    for (int j = 0; j < 8; ++j) betav[j] = beta[bn + tx*8 + j];

#pragma unroll
    for (int i = 0; i < 8; ++i) {
        const size_t row = (size_t)(bm + ty*8 + i);
#pragma unroll
        for (int j = 0; j < 8; ++j) {
            const float h = acc[i][j];
            float v = 0.f, ss = 0.f;
            for (int tt = 0; tt < T; ++tt) {
                v = fmaf(betav[j], v, h);     // v = beta*v + h
                if (v > 1.0f) { ss += 1.0f; v -= 1.0f; }  // fire + soft reset
            }
            rate[row * FDIM + (bn + tx*8 + j)] = __float2bfloat16(ss * invT); // exact k/8
        }
    }
}

// Kernel 2a: zero column-sum accumulator
__global__ void zero_colsum(float* __restrict__ colsum) {
    colsum[blockIdx.x * 256 + threadIdx.x] = 0.f;
}

// Kernel 2b: partial column sums of rate -> atomicAdd (exact multiples of 1/8, order-independent)
__global__ __launch_bounds__(256) void colsum_kernel(
    const __hip_bfloat16* __restrict__ rate, float* __restrict__ colsum)
{
    const int f  = blockIdx.x * 256 + threadIdx.x;
    const int n0 = blockIdx.y * 128;
    const unsigned short* r = (const unsigned short*)rate;
    float s = 0.f;
#pragma unroll 4
    for (int i = 0; i < 128; ++i)
        s += bf16bits_to_f32(r[(size_t)(n0 + i) * FDIM + f]);
    atomicAdd(&colsum[f], s);
}

// Kernel 2c: rate_per_unit[f] = colsum[f] / N_ROWS
__global__ void finalize_rpu(const float* __restrict__ colsum, float* __restrict__ out_rpu) {
    const int f = blockIdx.x * 256 + threadIdx.x;
    out_rpu[f] = colsum[f] * (1.0f / (float)N_ROWS);
}

// Kernel 3: out = rate @ w_down^T  (A: [N,F] bf16, B: [D,F] fp32, K=F)
__global__ __launch_bounds__(256) void down_kernel(
    const __hip_bfloat16* __restrict__ rate, const float* __restrict__ wdown,
    float* __restrict__ out)
{
    __shared__ float As[BK][BM];
    __shared__ float Bs[BK][BN];
    const int bm = blockIdx.y * BM;          // n rows
    const int bn = blockIdx.x * BN;          // d cols
    const int t  = threadIdx.x;
    const int tx = t & 15, ty = t >> 4;
    const int lr = t >> 1;
    const int lc = (t & 1) * 4;
    const unsigned short* Ap = (const unsigned short*)rate + (size_t)(bm + lr) * FDIM + lc;
    const float*          Bp = wdown + (size_t)(bn + lr) * FDIM + lc;

    float acc[8][8] = {};
    for (int k0 = 0; k0 < FDIM; k0 += BK) {
        ushort4 a = *(const ushort4*)(Ap + k0);
        float4  b = *(const float4*)(Bp + k0);
        __syncthreads();
        As[lc+0][lr] = bf16bits_to_f32(a.x);
        As[lc+1][lr] = bf16bits_to_f32(a.y);
        As[lc+2][lr] = bf16bits_to_f32(a.z);
        As[lc+3][lr] = bf16bits_to_f32(a.w);
        Bs[lc+0][lr] = b.x; Bs[lc+1][lr] = b.y; Bs[lc+2][lr] = b.z; Bs[lc+3][lr] = b.w;
        __syncthreads();
#pragma unroll
        for (int k = 0; k < BK; ++k) {
            float av[8], bv[8];
            *(float4*)&av[0] = *(const float4*)&As[k][ty*8];
            *(float4*)&av[4] = *(const float4*)&As[k][ty*8+4];
            *(float4*)&bv[0] = *(const float4*)&Bs[k][tx*8];
            *(float4*)&bv[4] = *(const float4*)&Bs[k][tx*8+4];
#pragma unroll
            for (int i = 0; i < 8; ++i)
#pragma unroll
                for (int j = 0; j < 8; ++j)
                    acc[i][j] = fmaf(av[i], bv[j], acc[i][j]);
        }
    }

#pragma unroll
    for (int i = 0; i < 8; ++i) {
        const size_t row = (size_t)(bm + ty*8 + i);
#pragma unroll
        for (int j = 0; j < 8; ++j)
            out[row * DDIM + (bn + tx*8 + j)] = acc[i][j];
    }
}

extern "C" void kernel_launch(void* const* d_in, const int* in_sizes, int n_in,
                              void* d_out, int out_size, void* d_ws, size_t ws_size,
                              hipStream_t stream) {
    const float* x     = (const float*)d_in[0];
    const float* wup   = (const float*)d_in[1];
    const float* wdown = (const float*)d_in[2];
    const float* beta  = (const float*)d_in[3];
    const int*   Tp    = (const int*)d_in[4];

    float* out     = (float*)d_out;                       // [N_ROWS, DDIM]
    float* out_rpu = out + (size_t)N_ROWS * DDIM;         // [FDIM]

    __hip_bfloat16* rate = (__hip_bfloat16*)d_ws;                          // [N_ROWS, FDIM] bf16
    float* colsum = (float*)((char*)d_ws + (size_t)N_ROWS * FDIM * 2);     // [FDIM] fp32

    up_spike_kernel<<<dim3(FDIM/BN, N_ROWS/BM), 256, 0, stream>>>(x, wup, beta, Tp, rate);
    zero_colsum<<<FDIM/256, 256, 0, stream>>>(colsum);
    colsum_kernel<<<dim3(FDIM/256, N_ROWS/128), 256, 0, stream>>>(rate, colsum);
    finalize_rpu<<<FDIM/256, 256, 0, stream>>>(colsum, out_rpu);
    down_kernel<<<dim3(DDIM/BN, N_ROWS/BM), 256, 0, stream>>>(rate, wdown, out);
}

// Round 2
// 252.678 us; speedup vs baseline: 3.9688x; 3.9688x over previous
//
#include <hip/hip_runtime.h>

// Dims fixed by setup_inputs: B=2, S=2048, D=1024, F=4096, T=8
#define N_ROWS 4096
#define DDIM   1024
#define FDIM   4096

typedef unsigned short ushort_t;
typedef __attribute__((ext_vector_type(8))) short bf16x8;
typedef __attribute__((ext_vector_type(4))) float f32x4;

#define MFMA(a, b, c) __builtin_amdgcn_mfma_f32_16x16x32_bf16((a), (b), (c), 0, 0, 0)

static __device__ __forceinline__ float bf16bits_to_f32(unsigned short u) {
    return __uint_as_float(((unsigned)u) << 16);
}
static __device__ __forceinline__ unsigned short f32_to_bf16_rn(float f) {
    unsigned u = __float_as_uint(f);
    unsigned r = 0x7fffu + ((u >> 16) & 1u);
    return (unsigned short)((u + r) >> 16);
}
static __device__ __forceinline__ void gload_lds16(const void* g, void* l) {
    __builtin_amdgcn_global_load_lds((const __attribute__((address_space(1))) unsigned*)g,
                                     (__attribute__((address_space(3))) unsigned*)l, 16, 0, 0);
}

// ---- split fp32 -> bf16 hi (+ optional lo residual) ----
__global__ __launch_bounds__(256) void split_kernel(
    const float* __restrict__ in, ushort_t* __restrict__ hi,
    ushort_t* __restrict__ lo, int n4)
{
    int i = blockIdx.x * 256 + threadIdx.x;
    const int stride = gridDim.x * 256;
    for (; i < n4; i += stride) {
        float4 v = ((const float4*)in)[i];
        ushort4 h;
        h.x = f32_to_bf16_rn(v.x); h.y = f32_to_bf16_rn(v.y);
        h.z = f32_to_bf16_rn(v.z); h.w = f32_to_bf16_rn(v.w);
        ((ushort4*)hi)[i] = h;
        if (lo) {
            ushort4 l;
            l.x = f32_to_bf16_rn(v.x - bf16bits_to_f32(h.x));
            l.y = f32_to_bf16_rn(v.y - bf16bits_to_f32(h.y));
            l.z = f32_to_bf16_rn(v.z - bf16bits_to_f32(h.z));
            l.w = f32_to_bf16_rn(v.w - bf16bits_to_f32(h.w));
            ((ushort4*)lo)[i] = l;
        }
    }
}

// ---- up-GEMM (split bf16, 3 MFMA products) + fused LIF -> rate (bf16) ----
__global__ __launch_bounds__(256) void up_mfma(
    const ushort_t* __restrict__ xh, const ushort_t* __restrict__ xl,
    const ushort_t* __restrict__ wh, const ushort_t* __restrict__ wl,
    const float* __restrict__ beta, const int* __restrict__ Tp,
    ushort_t* __restrict__ rate)
{
    __shared__ __align__(16) ushort_t Ah[128 * 32], Al[128 * 32];
    __shared__ __align__(16) ushort_t Bh[128 * 32], Bl[128 * 32];
    const int t = threadIdx.x;
    const int lane = t & 63, w = t >> 6;
    const int bm = blockIdx.y * 128, bn = blockIdx.x * 128;
    const int wr = (w >> 1) * 64, wc = (w & 1) * 64;

    const int sr = w * 32 + (lane >> 2);   // staging row (issue 0); issue 1 = +16
    const int sc = (lane & 3) * 8;         // staging col (elements)
    const size_t gA0 = (size_t)(bm + sr) * DDIM + sc, gA1 = gA0 + (size_t)16 * DDIM;
    const size_t gB0 = (size_t)(bn + sr) * DDIM + sc, gB1 = gB0 + (size_t)16 * DDIM;
    const int l0 = (w * 32) * 32, l1 = (w * 32 + 16) * 32;

    f32x4 acc[4][4];
#pragma unroll
    for (int m = 0; m < 4; ++m)
#pragma unroll
        for (int n = 0; n < 4; ++n) acc[m][n] = (f32x4){0.f, 0.f, 0.f, 0.f};

    for (int k0 = 0; k0 < DDIM; k0 += 32) {
        __syncthreads();
        gload_lds16(xh + gA0 + k0, &Ah[l0]);
        gload_lds16(xh + gA1 + k0, &Ah[l1]);
        gload_lds16(xl + gA0 + k0, &Al[l0]);
        gload_lds16(xl + gA1 + k0, &Al[l1]);
        gload_lds16(wh + gB0 + k0, &Bh[l0]);
        gload_lds16(wh + gB1 + k0, &Bh[l1]);
        gload_lds16(wl + gB0 + k0, &Bl[l0]);
        gload_lds16(wl + gB1 + k0, &Bl[l1]);
        __syncthreads();

        bf16x8 ah[4], al[4], bh[4], bl[4];
        const int ka = (lane >> 4) * 8;
#pragma unroll
        for (int m = 0; m < 4; ++m) {
            const int off = (wr + m * 16 + (lane & 15)) * 32 + ka;
            ah[m] = *(const bf16x8*)&Ah[off];
            al[m] = *(const bf16x8*)&Al[off];
        }
#pragma unroll
        for (int n = 0; n < 4; ++n) {
            const int off = (wc + n * 16 + (lane & 15)) * 32 + ka;
            bh[n] = *(const bf16x8*)&Bh[off];
            bl[n] = *(const bf16x8*)&Bl[off];
        }
#pragma unroll
        for (int m = 0; m < 4; ++m)
#pragma unroll
            for (int n = 0; n < 4; ++n) {
                acc[m][n] = MFMA(ah[m], bh[n], acc[m][n]);
                acc[m][n] = MFMA(ah[m], bl[n], acc[m][n]);
                acc[m][n] = MFMA(al[m], bh[n], acc[m][n]);
            }
    }

    const int T = Tp[0];
    const float invT = 1.0f / (float)T;
#pragma unroll
    for (int n = 0; n < 4; ++n) {
        const int f = bn + wc + n * 16 + (lane & 15);
        const float bet = beta[f];
#pragma unroll
        for (int m = 0; m < 4; ++m) {
            const int row0 = bm + wr + m * 16 + (lane >> 4) * 4;
#pragma unroll
            for (int r = 0; r < 4; ++r) {
                const float h = acc[m][n][r];
                float v = 0.f, ss = 0.f;
                for (int tt = 0; tt < T; ++tt) {
                    v = fmaf(bet, v, h);
                    if (v > 1.0f) { ss += 1.0f; v -= 1.0f; }
                }
                rate[(size_t)(row0 + r) * FDIM + f] = f32_to_bf16_rn(ss * invT);
            }
        }
    }
}

// ---- down-GEMM: out = rate(bf16) @ wd(bf16)^T, fp32 out ----
__global__ __launch_bounds__(256) void down_mfma(
    const ushort_t* __restrict__ rate, const ushort_t* __restrict__ wd,
    float* __restrict__ out)
{
    __shared__ __align__(16) ushort_t As[128 * 32], Bs[128 * 32];
    const int t = threadIdx.x;
    const int lane = t & 63, w = t >> 6;
    const int bm = blockIdx.y * 128, bn = blockIdx.x * 128;   // bn over DDIM
    const int wr = (w >> 1) * 64, wc = (w & 1) * 64;

    const int sr = w * 32 + (lane >> 2);
    const int sc = (lane & 3) * 8;
    const size_t gA0 = (size_t)(bm + sr) * FDIM + sc, gA1 = gA0 + (size_t)16 * FDIM;
    const size_t gB0 = (size_t)(bn + sr) * FDIM + sc, gB1 = gB0 + (size_t)16 * FDIM;
    const int l0 = (w * 32) * 32, l1 = (w * 32 + 16) * 32;

    f32x4 acc[4][4];
#pragma unroll
    for (int m = 0; m < 4; ++m)
#pragma unroll
        for (int n = 0; n < 4; ++n) acc[m][n] = (f32x4){0.f, 0.f, 0.f, 0.f};

    for (int k0 = 0; k0 < FDIM; k0 += 32) {
        __syncthreads();
        gload_lds16(rate + gA0 + k0, &As[l0]);
        gload_lds16(rate + gA1 + k0, &As[l1]);
        gload_lds16(wd + gB0 + k0, &Bs[l0]);
        gload_lds16(wd + gB1 + k0, &Bs[l1]);
        __syncthreads();

        bf16x8 a[4], b[4];
        const int ka = (lane >> 4) * 8;
#pragma unroll
        for (int m = 0; m < 4; ++m)
            a[m] = *(const bf16x8*)&As[(wr + m * 16 + (lane & 15)) * 32 + ka];
#pragma unroll
        for (int n = 0; n < 4; ++n)
            b[n] = *(const bf16x8*)&Bs[(wc + n * 16 + (lane & 15)) * 32 + ka];
#pragma unroll
        for (int m = 0; m < 4; ++m)
#pragma unroll
            for (int n = 0; n < 4; ++n)
                acc[m][n] = MFMA(a[m], b[n], acc[m][n]);
    }

#pragma unroll
    for (int n = 0; n < 4; ++n) {
        const int d = bn + wc + n * 16 + (lane & 15);
#pragma unroll
        for (int m = 0; m < 4; ++m) {
            const int row0 = bm + wr + m * 16 + (lane >> 4) * 4;
#pragma unroll
            for (int r = 0; r < 4; ++r)
                out[(size_t)(row0 + r) * DDIM + d] = acc[m][n][r];
        }
    }
}

// ---- rate_per_unit ----
__global__ void zero_colsum(float* __restrict__ colsum) {
    colsum[blockIdx.x * 256 + threadIdx.x] = 0.f;
}
__global__ __launch_bounds__(256) void colsum_kernel(
    const ushort_t* __restrict__ rate, float* __restrict__ colsum)
{
    const int f = blockIdx.x * 256 + threadIdx.x;
    const int n0 = blockIdx.y * 128;
    float s = 0.f;
#pragma unroll 4
    for (int i = 0; i < 128; ++i)
        s += bf16bits_to_f32(rate[(size_t)(n0 + i) * FDIM + f]);
    atomicAdd(&colsum[f], s);   // exact multiples of 1/8: order-independent
}
__global__ void finalize_rpu(const float* __restrict__ colsum, float* __restrict__ out_rpu) {
    const int f = blockIdx.x * 256 + threadIdx.x;
    out_rpu[f] = colsum[f] * (1.0f / (float)N_ROWS);
}

extern "C" void kernel_launch(void* const* d_in, const int* in_sizes, int n_in,
                              void* d_out, int out_size, void* d_ws, size_t ws_size,
                              hipStream_t stream) {
    const float* x     = (const float*)d_in[0];
    const float* wup   = (const float*)d_in[1];
    const float* wdown = (const float*)d_in[2];
    const float* beta  = (const float*)d_in[3];
    const int*   Tp    = (const int*)d_in[4];

    float* out     = (float*)d_out;
    float* out_rpu = out + (size_t)N_ROWS * DDIM;

    // workspace layout
    char* ws = (char*)d_ws;
    ushort_t* rate = (ushort_t*)ws;                                   // 33,554,432 B
    ushort_t* xh   = (ushort_t*)(ws + 33554432);                      //  8,388,608 B
    ushort_t* xl   = (ushort_t*)(ws + 33554432 + 8388608);            //  8,388,608 B
    ushort_t* wuph = (ushort_t*)(ws + 33554432 + 2 * 8388608);        //  8,388,608 B
    ushort_t* wupl = (ushort_t*)(ws + 33554432 + 3 * 8388608);        //  8,388,608 B
    float*    colsum = (float*)(ws + 33554432 + 4 * 8388608);         //     16,384 B
    ushort_t* wdh  = xh;  // reuse xh region after up_mfma consumed it

    const int n4 = (N_ROWS * DDIM) / 4;  // 1,048,576 (same count for all three)

    split_kernel<<<2048, 256, 0, stream>>>(x, xh, xl, n4);
    split_kernel<<<2048, 256, 0, stream>>>(wup, wuph, wupl, n4);

    up_mfma<<<dim3(FDIM / 128, N_ROWS / 128), 256, 0, stream>>>(
        xh, xl, wuph, wupl, beta, Tp, rate);

    split_kernel<<<2048, 256, 0, stream>>>(wdown, wdh, nullptr, n4);

    zero_colsum<<<FDIM / 256, 256, 0, stream>>>(colsum);
    colsum_kernel<<<dim3(FDIM / 256, N_ROWS / 128), 256, 0, stream>>>(rate, colsum);
    finalize_rpu<<<FDIM / 256, 256, 0, stream>>>(colsum, out_rpu);

    down_mfma<<<dim3(DDIM / 128, N_ROWS / 128), 256, 0, stream>>>(rate, wdh, out);
}

// Round 3
// 206.280 us; speedup vs baseline: 4.8614x; 1.2249x over previous
//
#include <hip/hip_runtime.h>

// Dims fixed by setup_inputs: B=2, S=2048, D=1024, F=4096, T=8
#define N_ROWS 4096
#define DDIM   1024
#define FDIM   4096

typedef unsigned short u16;
typedef __attribute__((ext_vector_type(8))) short bf16x8;
typedef __attribute__((ext_vector_type(4))) float f32x4;

#define MFMA(a, b, c) __builtin_amdgcn_mfma_f32_16x16x32_bf16((a), (b), (c), 0, 0, 0)

static __device__ __forceinline__ float bf16bits_to_f32(unsigned short u) {
    return __uint_as_float(((unsigned)u) << 16);
}
static __device__ __forceinline__ unsigned short f32_to_bf16_rn(float f) {
    unsigned u = __float_as_uint(f);
    unsigned r = 0x7fffu + ((u >> 16) & 1u);
    return (unsigned short)((u + r) >> 16);
}
static __device__ __forceinline__ void gload_lds16(const u16* g, u16* l) {
    __builtin_amdgcn_global_load_lds((const __attribute__((address_space(1))) unsigned*)g,
                                     (__attribute__((address_space(3))) unsigned*)l, 16, 0, 0);
}

// ---- split fp32 -> bf16 hi (+ optional lo residual) ----
__global__ __launch_bounds__(256) void split_kernel(
    const float* __restrict__ in, u16* __restrict__ hi,
    u16* __restrict__ lo, int n4)
{
    int i = blockIdx.x * 256 + threadIdx.x;
    const int stride = gridDim.x * 256;
    for (; i < n4; i += stride) {
        float4 v = ((const float4*)in)[i];
        ushort4 h;
        h.x = f32_to_bf16_rn(v.x); h.y = f32_to_bf16_rn(v.y);
        h.z = f32_to_bf16_rn(v.z); h.w = f32_to_bf16_rn(v.w);
        ((ushort4*)hi)[i] = h;
        if (lo) {
            ushort4 l;
            l.x = f32_to_bf16_rn(v.x - bf16bits_to_f32(h.x));
            l.y = f32_to_bf16_rn(v.y - bf16bits_to_f32(h.y));
            l.z = f32_to_bf16_rn(v.z - bf16bits_to_f32(h.z));
            l.w = f32_to_bf16_rn(v.w - bf16bits_to_f32(h.w));
            ((ushort4*)lo)[i] = l;
        }
    }
}

// ---- up-GEMM: 256x256 tile, BK=32, 8 waves, double-buffered counted-vmcnt
//      schedule, swizzled LDS (pre-swizzled global source), split-bf16 (3 MFMA
//      products), fused LIF + column-sum epilogue. ----
__global__ __launch_bounds__(512, 2) void up_mfma(
    const u16* __restrict__ xh, const u16* __restrict__ xl,
    const u16* __restrict__ wh, const u16* __restrict__ wl,
    const float* __restrict__ beta, const int* __restrict__ Tp,
    u16* __restrict__ rate, float* __restrict__ colsum)
{
    // [slot 2][buf 4: Ah,Al,Bh,Bl][8192 u16 = 256 rows x 32 k] = 128 KiB
    __shared__ __align__(16) u16 lds[2 * 4 * 8192];

    const int t = threadIdx.x;
    const int l = t & 63, w = t >> 6;           // 8 waves
    const int wm = w >> 2, wn = w & 3;          // 2 (M) x 4 (N)
    const int bm = blockIdx.y * 256, bn = blockIdx.x * 256;

    // ---- staging addressing (per-thread constant) ----
    // LDS dest (linear): buf*8192 + j*4096 + t*8  (u16), i.e. row=j*128+(t>>2), phys slot=t&3
    // swizzle: phys_slot = log_slot ^ ((row>>1)&3); row>>1&3 == (t>>3)&3
    const int srow = t >> 2;                               // 0..127
    const int koff = (((t & 3) ^ ((t >> 3) & 3)) << 3);    // source k offset (elements)
    const size_t gA[2] = { (size_t)(bm + srow) * DDIM + koff,
                           (size_t)(bm + 128 + srow) * DDIM + koff };
    const size_t gB[2] = { (size_t)(bn + srow) * DDIM + koff,
                           (size_t)(bn + 128 + srow) * DDIM + koff };
    const int dst = t * 8;                                  // u16 units within 8KiB issue

#define STAGE(step, slot) do {                                                   \
    const int k0_ = (step) << 5;                                                 \
    u16* Lb_ = &lds[(slot) * 32768];                                             \
    gload_lds16(xh + gA[0] + k0_, Lb_ + 0 * 8192 + 0 * 4096 + dst);              \
    gload_lds16(xh + gA[1] + k0_, Lb_ + 0 * 8192 + 1 * 4096 + dst);              \
    gload_lds16(xl + gA[0] + k0_, Lb_ + 1 * 8192 + 0 * 4096 + dst);              \
    gload_lds16(xl + gA[1] + k0_, Lb_ + 1 * 8192 + 1 * 4096 + dst);              \
    gload_lds16(wh + gB[0] + k0_, Lb_ + 2 * 8192 + 0 * 4096 + dst);              \
    gload_lds16(wh + gB[1] + k0_, Lb_ + 2 * 8192 + 1 * 4096 + dst);              \
    gload_lds16(wl + gB[0] + k0_, Lb_ + 3 * 8192 + 0 * 4096 + dst);              \
    gload_lds16(wl + gB[1] + k0_, Lb_ + 3 * 8192 + 1 * 4096 + dst);              \
} while (0)

    // ---- fragment read addressing (per-lane constant swizzle) ----
    const int lr = l & 15, lk = l >> 4;
    const int psl = ((lk ^ ((lr >> 1) & 3)) << 3);          // swizzled 16B slot, u16 units
    // A-frag(buf,m): row = wm*128 + m*16 + lr ; B-frag(buf,n): row = wn*64 + n*16 + lr

    f32x4 acc[8][4];
#pragma unroll
    for (int m = 0; m < 8; ++m)
#pragma unroll
        for (int n = 0; n < 4; ++n) acc[m][n] = (f32x4){0.f, 0.f, 0.f, 0.f};

    // prologue: fill both slots, wait for slot 0
    STAGE(0, 0);
    STAGE(1, 1);
    asm volatile("s_waitcnt vmcnt(8)" ::: "memory");
    __builtin_amdgcn_s_barrier();
    __builtin_amdgcn_sched_barrier(0);

    const int NT = DDIM / 32;   // 32
#pragma unroll 1
    for (int ts = 0; ts < NT; ++ts) {
        const int sb = (ts & 1) * 32768;

        bf16x8 bh[4], bl[4];
#pragma unroll
        for (int n = 0; n < 4; ++n) {
            const int ro = sb + (wn * 64 + n * 16 + lr) * 32 + psl;
            bh[n] = *(const bf16x8*)&lds[ro + 2 * 8192];
            bl[n] = *(const bf16x8*)&lds[ro + 3 * 8192];
        }
#pragma unroll
        for (int mh = 0; mh < 2; ++mh) {
            bf16x8 ah[4], al[4];
#pragma unroll
            for (int mi = 0; mi < 4; ++mi) {
                const int ro = sb + (wm * 128 + (mh * 4 + mi) * 16 + lr) * 32 + psl;
                ah[mi] = *(const bf16x8*)&lds[ro];
                al[mi] = *(const bf16x8*)&lds[ro + 8192];
            }
            __builtin_amdgcn_s_setprio(1);
#pragma unroll
            for (int mi = 0; mi < 4; ++mi)
#pragma unroll
                for (int n = 0; n < 4; ++n) {
                    f32x4 c = acc[mh * 4 + mi][n];
                    c = MFMA(ah[mi], bh[n], c);
                    c = MFMA(ah[mi], bl[n], c);
                    c = MFMA(al[mi], bh[n], c);
                    acc[mh * 4 + mi][n] = c;
                }
            __builtin_amdgcn_s_setprio(0);
        }

        if (ts == NT - 1) break;

        __builtin_amdgcn_s_barrier();            // all reads of this slot done
        __builtin_amdgcn_sched_barrier(0);
        if (ts + 2 < NT) {
            STAGE(ts + 2, ts & 1);               // overwrite just-consumed slot
            asm volatile("s_waitcnt vmcnt(8)" ::: "memory");   // next slot landed
        } else {
            asm volatile("s_waitcnt vmcnt(0)" ::: "memory");   // drain tail
        }
        __builtin_amdgcn_s_barrier();
        __builtin_amdgcn_sched_barrier(0);
    }
#undef STAGE

    // ---- epilogue: LIF recurrence, rate write, fused column sums ----
    const int T = Tp[0];
    const float invT = 1.0f / (float)T;
#pragma unroll
    for (int n = 0; n < 4; ++n) {
        const int f = bn + wn * 64 + n * 16 + lr;
        const float bet = beta[f];
        float colacc = 0.f;
#pragma unroll
        for (int m = 0; m < 8; ++m) {
            const int row0 = bm + wm * 128 + m * 16 + lk * 4;
#pragma unroll
            for (int r = 0; r < 4; ++r) {
                const float h = acc[m][n][r];
                float v = 0.f, ss = 0.f;
                if (T == 8) {
#pragma unroll
                    for (int tt = 0; tt < 8; ++tt) {
                        v = fmaf(bet, v, h);
                        float s = (v > 1.0f) ? 1.0f : 0.0f;
                        ss += s; v -= s;
                    }
                } else {
                    for (int tt = 0; tt < T; ++tt) {
                        v = fmaf(bet, v, h);
                        float s = (v > 1.0f) ? 1.0f : 0.0f;
                        ss += s; v -= s;
                    }
                }
                const float rv = ss * invT;                 // exact k/8
                rate[(size_t)(row0 + r) * FDIM + f] = f32_to_bf16_rn(rv);
                colacc += rv;
            }
        }
        // reduce over the 4 lane-quarters (lanes l, l^16, l^32, l^48 share f)
        colacc += __shfl_xor(colacc, 16, 64);
        colacc += __shfl_xor(colacc, 32, 64);
        if (lk == 0) atomicAdd(&colsum[f], colacc);          // exact eighths
    }
}

// ---- down-GEMM: out = rate(bf16) @ wd(bf16)^T, fp32 out (m97-style 128^2) ----
__global__ __launch_bounds__(256) void down_mfma(
    const u16* __restrict__ rate, const u16* __restrict__ wd,
    float* __restrict__ out)
{
    __shared__ __align__(16) u16 As[128 * 32], Bs[128 * 32];
    const int t = threadIdx.x;
    const int lane = t & 63, w = t >> 6;
    const int bm = blockIdx.y * 128, bn = blockIdx.x * 128;   // bn over DDIM
    const int wr = (w >> 1) * 64, wc = (w & 1) * 64;

    const int sr = w * 32 + (lane >> 2);
    const int sc = (lane & 3) * 8;
    const size_t gA0 = (size_t)(bm + sr) * FDIM + sc, gA1 = gA0 + (size_t)16 * FDIM;
    const size_t gB0 = (size_t)(bn + sr) * FDIM + sc, gB1 = gB0 + (size_t)16 * FDIM;
    const int l0 = (w * 32) * 32, l1 = (w * 32 + 16) * 32;

    f32x4 acc[4][4];
#pragma unroll
    for (int m = 0; m < 4; ++m)
#pragma unroll
        for (int n = 0; n < 4; ++n) acc[m][n] = (f32x4){0.f, 0.f, 0.f, 0.f};

    for (int k0 = 0; k0 < FDIM; k0 += 32) {
        __syncthreads();
        gload_lds16(rate + gA0 + k0, &As[l0]);
        gload_lds16(rate + gA1 + k0, &As[l1]);
        gload_lds16(wd + gB0 + k0, &Bs[l0]);
        gload_lds16(wd + gB1 + k0, &Bs[l1]);
        __syncthreads();

        bf16x8 a[4], b[4];
        const int ka = (lane >> 4) * 8;
#pragma unroll
        for (int m = 0; m < 4; ++m)
            a[m] = *(const bf16x8*)&As[(wr + m * 16 + (lane & 15)) * 32 + ka];
#pragma unroll
        for (int n = 0; n < 4; ++n)
            b[n] = *(const bf16x8*)&Bs[(wc + n * 16 + (lane & 15)) * 32 + ka];
#pragma unroll
        for (int m = 0; m < 4; ++m)
#pragma unroll
            for (int n = 0; n < 4; ++n)
                acc[m][n] = MFMA(a[m], b[n], acc[m][n]);
    }

#pragma unroll
    for (int n = 0; n < 4; ++n) {
        const int d = bn + wc + n * 16 + (lane & 15);
#pragma unroll
        for (int m = 0; m < 4; ++m) {
            const int row0 = bm + wr + m * 16 + (lane >> 4) * 4;
#pragma unroll
            for (int r = 0; r < 4; ++r)
                out[(size_t)(row0 + r) * DDIM + d] = acc[m][n][r];
        }
    }
}

// ---- rate_per_unit helpers ----
__global__ void zero_colsum(float* __restrict__ colsum) {
    colsum[blockIdx.x * 256 + threadIdx.x] = 0.f;
}
__global__ void finalize_rpu(const float* __restrict__ colsum, float* __restrict__ out_rpu) {
    const int f = blockIdx.x * 256 + threadIdx.x;
    out_rpu[f] = colsum[f] * (1.0f / (float)N_ROWS);
}

extern "C" void kernel_launch(void* const* d_in, const int* in_sizes, int n_in,
                              void* d_out, int out_size, void* d_ws, size_t ws_size,
                              hipStream_t stream) {
    const float* x     = (const float*)d_in[0];
    const float* wup   = (const float*)d_in[1];
    const float* wdown = (const float*)d_in[2];
    const float* beta  = (const float*)d_in[3];
    const int*   Tp    = (const int*)d_in[4];

    float* out     = (float*)d_out;
    float* out_rpu = out + (size_t)N_ROWS * DDIM;

    char* ws = (char*)d_ws;
    u16* rate = (u16*)ws;                                   // 33,554,432 B
    u16* xh   = (u16*)(ws + 33554432);
    u16* xl   = (u16*)(ws + 33554432 + 8388608);
    u16* wuph = (u16*)(ws + 33554432 + 2 * 8388608);
    u16* wupl = (u16*)(ws + 33554432 + 3 * 8388608);
    float* colsum = (float*)(ws + 33554432 + 4 * 8388608);
    u16* wdh  = xh;   // reuse xh region after up_mfma consumed it

    const int n4 = (N_ROWS * DDIM) / 4;

    split_kernel<<<2048, 256, 0, stream>>>(x, xh, xl, n4);
    split_kernel<<<2048, 256, 0, stream>>>(wup, wuph, wupl, n4);
    zero_colsum<<<FDIM / 256, 256, 0, stream>>>(colsum);

    up_mfma<<<dim3(FDIM / 256, N_ROWS / 256), 512, 0, stream>>>(
        xh, xl, wuph, wupl, beta, Tp, rate, colsum);

    split_kernel<<<2048, 256, 0, stream>>>(wdown, wdh, nullptr, n4);
    finalize_rpu<<<FDIM / 256, 256, 0, stream>>>(colsum, out_rpu);

    down_mfma<<<dim3(DDIM / 128, N_ROWS / 128), 256, 0, stream>>>(rate, wdh, out);
}

// Round 4
// 202.436 us; speedup vs baseline: 4.9537x; 1.0190x over previous
//
#include <hip/hip_runtime.h>

// Dims fixed by setup_inputs: B=2, S=2048, D=1024, F=4096, T=8
#define N_ROWS 4096
#define DDIM   1024
#define FDIM   4096

typedef unsigned short u16;
typedef __attribute__((ext_vector_type(8))) short bf16x8;
typedef __attribute__((ext_vector_type(4))) float f32x4;

#define MFMA(a, b, c) __builtin_amdgcn_mfma_f32_16x16x32_bf16((a), (b), (c), 0, 0, 0)

static __device__ __forceinline__ float bf16bits_to_f32(unsigned short u) {
    return __uint_as_float(((unsigned)u) << 16);
}
static __device__ __forceinline__ unsigned short f32_to_bf16_rn(float f) {
    unsigned u = __float_as_uint(f);
    unsigned r = 0x7fffu + ((u >> 16) & 1u);
    return (unsigned short)((u + r) >> 16);
}
static __device__ __forceinline__ void gload_lds16(const u16* g, u16* l) {
    __builtin_amdgcn_global_load_lds((const __attribute__((address_space(1))) unsigned*)g,
                                     (__attribute__((address_space(3))) unsigned*)l, 16, 0, 0);
}

// ---- split fp32 -> bf16 hi (+ optional lo residual) ----
__global__ __launch_bounds__(256) void split_kernel(
    const float* __restrict__ in, u16* __restrict__ hi,
    u16* __restrict__ lo, int n4)
{
    int i = blockIdx.x * 256 + threadIdx.x;
    const int stride = gridDim.x * 256;
    for (; i < n4; i += stride) {
        float4 v = ((const float4*)in)[i];
        ushort4 h;
        h.x = f32_to_bf16_rn(v.x); h.y = f32_to_bf16_rn(v.y);
        h.z = f32_to_bf16_rn(v.z); h.w = f32_to_bf16_rn(v.w);
        ((ushort4*)hi)[i] = h;
        if (lo) {
            ushort4 l;
            l.x = f32_to_bf16_rn(v.x - bf16bits_to_f32(h.x));
            l.y = f32_to_bf16_rn(v.y - bf16bits_to_f32(h.y));
            l.z = f32_to_bf16_rn(v.z - bf16bits_to_f32(h.z));
            l.w = f32_to_bf16_rn(v.w - bf16bits_to_f32(h.w));
            ((ushort4*)lo)[i] = l;
        }
    }
}

// ---- up-GEMM: 256x256 tile, BK=32, 8 waves, 4-phase-per-K-tile interleaved
//      schedule (T3+T4), swizzled LDS, split-bf16 (3 MFMA products),
//      fused LIF + column-sum epilogue. ----
__global__ __launch_bounds__(512, 2) void up_mfma(
    const u16* __restrict__ xh, const u16* __restrict__ xl,
    const u16* __restrict__ wh, const u16* __restrict__ wl,
    const float* __restrict__ beta, const int* __restrict__ Tp,
    u16* __restrict__ rate, float* __restrict__ colsum)
{
    // [slot 2][buf 4: Ah,Al,Bh,Bl][8192 u16 = 256 rows x 32 k] = 128 KiB
    __shared__ __align__(16) u16 lds[2 * 4 * 8192];

    const int t = threadIdx.x;
    const int l = t & 63, w = t >> 6;           // 8 waves
    const int wm = w >> 2, wn = w & 3;          // 2 (M) x 4 (N)
    const int bm = blockIdx.y * 256, bn = blockIdx.x * 256;

    // staging: LDS dest linear (t*8 u16 within an 8KiB half-issue);
    // source k pre-swizzled so read-side XOR recovers it (involution).
    const int srow = t >> 2;                               // 0..127
    const int koff = (((t & 3) ^ ((t >> 3) & 3)) << 3);
    const size_t gA0 = (size_t)(bm + srow) * DDIM + koff;
    const size_t gA1 = (size_t)(bm + 128 + srow) * DDIM + koff;
    const size_t gB0 = (size_t)(bn + srow) * DDIM + koff;
    const size_t gB1 = (size_t)(bn + 128 + srow) * DDIM + koff;
    const int dst = t * 8;

#define ST(arr, g, buf, half, slot, step) \
    gload_lds16((arr) + (g) + ((size_t)(step) << 5), \
                &lds[(slot) * 32768 + (buf) * 8192 + (half) * 4096 + dst])

    // fragment read addressing (swizzled 16B slot)
    const int lr = l & 15, lk = l >> 4;
    const int psl = ((lk ^ ((lr >> 1) & 3)) << 3);

    f32x4 acc[8][4];
#pragma unroll
    for (int m = 0; m < 8; ++m)
#pragma unroll
        for (int n = 0; n < 4; ++n) acc[m][n] = (f32x4){0.f, 0.f, 0.f, 0.f};

#define RD_A(MH) \
    _Pragma("unroll") for (int mi = 0; mi < 4; ++mi) { \
        const int ro = sb + (wm * 128 + ((MH) * 4 + mi) * 16 + lr) * 32 + psl; \
        ah[mi] = *(const bf16x8*)&lds[ro]; \
        al[mi] = *(const bf16x8*)&lds[ro + 8192]; }

#define RD_B(NH) \
    _Pragma("unroll") for (int ni = 0; ni < 2; ++ni) { \
        const int ro = sb + (wn * 64 + ((NH) * 2 + ni) * 16 + lr) * 32 + psl; \
        bh[ni] = *(const bf16x8*)&lds[ro + 2 * 8192]; \
        bl[ni] = *(const bf16x8*)&lds[ro + 3 * 8192]; }

#define CLUSTER(MH, NB) \
    __builtin_amdgcn_s_setprio(1); \
    _Pragma("unroll") for (int mi = 0; mi < 4; ++mi) \
    _Pragma("unroll") for (int ni = 0; ni < 2; ++ni) { \
        f32x4 c = acc[(MH) * 4 + mi][(NB) + ni]; \
        c = MFMA(ah[mi], bh[ni], c); \
        c = MFMA(ah[mi], bl[ni], c); \
        c = MFMA(al[mi], bh[ni], c); \
        acc[(MH) * 4 + mi][(NB) + ni] = c; } \
    __builtin_amdgcn_s_setprio(0);

#define PHASE_SYNC() \
    __builtin_amdgcn_s_barrier(); \
    asm volatile("s_waitcnt lgkmcnt(0)" ::: "memory"); \
    __builtin_amdgcn_sched_barrier(0);

    // prologue: stage tile 0 into slot 0, drain, barrier
    ST(xh, gA0, 0, 0, 0, 0); ST(xh, gA1, 0, 1, 0, 0);
    ST(xl, gA0, 1, 0, 0, 0); ST(xl, gA1, 1, 1, 0, 0);
    ST(wh, gB0, 2, 0, 0, 0); ST(wh, gB1, 2, 1, 0, 0);
    ST(wl, gB0, 3, 0, 0, 0); ST(wl, gB1, 3, 1, 0, 0);
    asm volatile("s_waitcnt vmcnt(0)" ::: "memory");
    __builtin_amdgcn_s_barrier();

    const int NT = DDIM / 32;   // 32
#pragma unroll 1
    for (int ts = 0; ts < NT; ++ts) {
        const int sb = (ts & 1) * 32768;
        const int ns = (ts + 1) & 1;
        const bool more = (ts + 1 < NT);
        bf16x8 ah[4], al[4], bh[2], bl[2];

        // phase 0: quadrant (mh0, nh0); stage 3 of next tile
        RD_A(0); RD_B(0);
        if (more) {
            ST(xh, gA0, 0, 0, ns, ts + 1); ST(xh, gA1, 0, 1, ns, ts + 1);
            ST(xl, gA0, 1, 0, ns, ts + 1);
        }
        PHASE_SYNC();
        CLUSTER(0, 0);
        __builtin_amdgcn_s_barrier();

        // phase 1: quadrant (mh0, nh1); A held, read B1; stage 3
        RD_B(1);
        if (more) {
            ST(xl, gA1, 1, 1, ns, ts + 1);
            ST(wh, gB0, 2, 0, ns, ts + 1); ST(wh, gB1, 2, 1, ns, ts + 1);
        }
        PHASE_SYNC();
        CLUSTER(0, 2);
        __builtin_amdgcn_s_barrier();

        // phase 2: quadrant (mh1, nh1); B1 held, read A1; stage 2
        RD_A(1);
        if (more) {
            ST(wl, gB0, 3, 0, ns, ts + 1); ST(wl, gB1, 3, 1, ns, ts + 1);
        }
        PHASE_SYNC();
        CLUSTER(1, 2);
        __builtin_amdgcn_s_barrier();

        // phase 3: quadrant (mh1, nh0); A1 held, re-read B0; no stage
        RD_B(0);
        PHASE_SYNC();
        CLUSTER(1, 0);
        // tile boundary: own loads for tile ts+1 landed, then sync all waves
        asm volatile("s_waitcnt vmcnt(0)" ::: "memory");
        __builtin_amdgcn_s_barrier();
    }
#undef ST
#undef RD_A
#undef RD_B
#undef CLUSTER
#undef PHASE_SYNC

    // ---- epilogue: LIF recurrence, rate write, fused column sums ----
    const int T = Tp[0];
    const float invT = 1.0f / (float)T;
#pragma unroll
    for (int n = 0; n < 4; ++n) {
        const int f = bn + wn * 64 + n * 16 + lr;
        const float bet = beta[f];
        float colacc = 0.f;
#pragma unroll
        for (int m = 0; m < 8; ++m) {
            const int row0 = bm + wm * 128 + m * 16 + lk * 4;
#pragma unroll
            for (int r = 0; r < 4; ++r) {
                const float h = acc[m][n][r];
                float v = 0.f, ss = 0.f;
                if (T == 8) {
#pragma unroll
                    for (int tt = 0; tt < 8; ++tt) {
                        v = fmaf(bet, v, h);
                        float s = (v > 1.0f) ? 1.0f : 0.0f;
                        ss += s; v -= s;
                    }
                } else {
                    for (int tt = 0; tt < T; ++tt) {
                        v = fmaf(bet, v, h);
                        float s = (v > 1.0f) ? 1.0f : 0.0f;
                        ss += s; v -= s;
                    }
                }
                const float rv = ss * invT;                 // exact k/8
                rate[(size_t)(row0 + r) * FDIM + f] = f32_to_bf16_rn(rv);
                colacc += rv;
            }
        }
        colacc += __shfl_xor(colacc, 16, 64);
        colacc += __shfl_xor(colacc, 32, 64);
        if (lk == 0) atomicAdd(&colsum[f], colacc);          // exact eighths
    }
}

// ---- down-GEMM: out = rate(bf16) @ wd(bf16)^T, fp32 out (m97-style 128^2) ----
__global__ __launch_bounds__(256) void down_mfma(
    const u16* __restrict__ rate, const u16* __restrict__ wd,
    float* __restrict__ out)
{
    __shared__ __align__(16) u16 As[128 * 32], Bs[128 * 32];
    const int t = threadIdx.x;
    const int lane = t & 63, w = t >> 6;
    const int bm = blockIdx.y * 128, bn = blockIdx.x * 128;   // bn over DDIM
    const int wr = (w >> 1) * 64, wc = (w & 1) * 64;

    const int sr = w * 32 + (lane >> 2);
    const int sc = (lane & 3) * 8;
    const size_t gA0 = (size_t)(bm + sr) * FDIM + sc, gA1 = gA0 + (size_t)16 * FDIM;
    const size_t gB0 = (size_t)(bn + sr) * FDIM + sc, gB1 = gB0 + (size_t)16 * FDIM;
    const int l0 = (w * 32) * 32, l1 = (w * 32 + 16) * 32;

    f32x4 acc[4][4];
#pragma unroll
    for (int m = 0; m < 4; ++m)
#pragma unroll
        for (int n = 0; n < 4; ++n) acc[m][n] = (f32x4){0.f, 0.f, 0.f, 0.f};

    for (int k0 = 0; k0 < FDIM; k0 += 32) {
        __syncthreads();
        gload_lds16(rate + gA0 + k0, &As[l0]);
        gload_lds16(rate + gA1 + k0, &As[l1]);
        gload_lds16(wd + gB0 + k0, &Bs[l0]);
        gload_lds16(wd + gB1 + k0, &Bs[l1]);
        __syncthreads();

        bf16x8 a[4], b[4];
        const int ka = (lane >> 4) * 8;
#pragma unroll
        for (int m = 0; m < 4; ++m)
            a[m] = *(const bf16x8*)&As[(wr + m * 16 + (lane & 15)) * 32 + ka];
#pragma unroll
        for (int n = 0; n < 4; ++n)
            b[n] = *(const bf16x8*)&Bs[(wc + n * 16 + (lane & 15)) * 32 + ka];
#pragma unroll
        for (int m = 0; m < 4; ++m)
#pragma unroll
            for (int n = 0; n < 4; ++n)
                acc[m][n] = MFMA(a[m], b[n], acc[m][n]);
    }

#pragma unroll
    for (int n = 0; n < 4; ++n) {
        const int d = bn + wc + n * 16 + (lane & 15);
#pragma unroll
        for (int m = 0; m < 4; ++m) {
            const int row0 = bm + wr + m * 16 + (lane >> 4) * 4;
#pragma unroll
            for (int r = 0; r < 4; ++r)
                out[(size_t)(row0 + r) * DDIM + d] = acc[m][n][r];
        }
    }
}

// ---- rate_per_unit helpers ----
__global__ void zero_colsum(float* __restrict__ colsum) {
    colsum[blockIdx.x * 256 + threadIdx.x] = 0.f;
}
__global__ void finalize_rpu(const float* __restrict__ colsum, float* __restrict__ out_rpu) {
    const int f = blockIdx.x * 256 + threadIdx.x;
    out_rpu[f] = colsum[f] * (1.0f / (float)N_ROWS);
}

extern "C" void kernel_launch(void* const* d_in, const int* in_sizes, int n_in,
                              void* d_out, int out_size, void* d_ws, size_t ws_size,
                              hipStream_t stream) {
    const float* x     = (const float*)d_in[0];
    const float* wup   = (const float*)d_in[1];
    const float* wdown = (const float*)d_in[2];
    const float* beta  = (const float*)d_in[3];
    const int*   Tp    = (const int*)d_in[4];

    float* out     = (float*)d_out;
    float* out_rpu = out + (size_t)N_ROWS * DDIM;

    char* ws = (char*)d_ws;
    u16* rate = (u16*)ws;                                   // 33,554,432 B
    u16* xh   = (u16*)(ws + 33554432);
    u16* xl   = (u16*)(ws + 33554432 + 8388608);
    u16* wuph = (u16*)(ws + 33554432 + 2 * 8388608);
    u16* wupl = (u16*)(ws + 33554432 + 3 * 8388608);
    float* colsum = (float*)(ws + 33554432 + 4 * 8388608);
    u16* wdh  = xh;   // reuse xh region after up_mfma consumed it

    const int n4 = (N_ROWS * DDIM) / 4;

    split_kernel<<<2048, 256, 0, stream>>>(x, xh, xl, n4);
    split_kernel<<<2048, 256, 0, stream>>>(wup, wuph, wupl, n4);
    zero_colsum<<<FDIM / 256, 256, 0, stream>>>(colsum);

    up_mfma<<<dim3(FDIM / 256, N_ROWS / 256), 512, 0, stream>>>(
        xh, xl, wuph, wupl, beta, Tp, rate, colsum);

    split_kernel<<<2048, 256, 0, stream>>>(wdown, wdh, nullptr, n4);
    finalize_rpu<<<FDIM / 256, 256, 0, stream>>>(colsum, out_rpu);

    down_mfma<<<dim3(DDIM / 128, N_ROWS / 128), 256, 0, stream>>>(rate, wdh, out);
}

// Round 5
// 188.510 us; speedup vs baseline: 5.3197x; 1.0739x over previous
//
#include <hip/hip_runtime.h>

// Dims fixed by setup_inputs: B=2, S=2048, D=1024, F=4096, T=8
#define N_ROWS 4096
#define DDIM   1024
#define FDIM   4096

typedef unsigned short u16;
typedef __attribute__((ext_vector_type(8))) short bf16x8;
typedef __attribute__((ext_vector_type(16))) float f32x16;

#define MFMA32(a, b, c) __builtin_amdgcn_mfma_f32_32x32x16_bf16((a), (b), (c), 0, 0, 0)

static __device__ __forceinline__ float bf16bits_to_f32(unsigned short u) {
    return __uint_as_float(((unsigned)u) << 16);
}
static __device__ __forceinline__ unsigned short f32_to_bf16_rn(float f) {
    unsigned u = __float_as_uint(f);
    unsigned r = 0x7fffu + ((u >> 16) & 1u);
    return (unsigned short)((u + r) >> 16);
}
static __device__ __forceinline__ void gload_lds16(const u16* g, u16* l) {
    __builtin_amdgcn_global_load_lds((const __attribute__((address_space(1))) unsigned*)g,
                                     (__attribute__((address_space(3))) unsigned*)l, 16, 0, 0);
}

// ---- split fp32 -> bf16 hi (+ optional lo residual) ----
__global__ __launch_bounds__(256) void split_kernel(
    const float* __restrict__ in, u16* __restrict__ hi,
    u16* __restrict__ lo, int n4)
{
    int i = blockIdx.x * 256 + threadIdx.x;
    const int stride = gridDim.x * 256;
    for (; i < n4; i += stride) {
        float4 v = ((const float4*)in)[i];
        ushort4 h;
        h.x = f32_to_bf16_rn(v.x); h.y = f32_to_bf16_rn(v.y);
        h.z = f32_to_bf16_rn(v.z); h.w = f32_to_bf16_rn(v.w);
        ((ushort4*)hi)[i] = h;
        if (lo) {
            ushort4 l;
            l.x = f32_to_bf16_rn(v.x - bf16bits_to_f32(h.x));
            l.y = f32_to_bf16_rn(v.y - bf16bits_to_f32(h.y));
            l.z = f32_to_bf16_rn(v.z - bf16bits_to_f32(h.z));
            l.w = f32_to_bf16_rn(v.w - bf16bits_to_f32(h.w));
            ((ushort4*)lo)[i] = l;
        }
    }
}

// ---- up-GEMM: 256x256 tile, BK=32, 8 waves, 32x32x16 MFMA, 2 phases/tile
//      (M-split, B held in regs), split-bf16 (3 products), swizzled LDS,
//      fused LIF + column-sum epilogue. ----
__global__ __launch_bounds__(512, 2) void up_mfma(
    const u16* __restrict__ xh, const u16* __restrict__ xl,
    const u16* __restrict__ wh, const u16* __restrict__ wl,
    const float* __restrict__ beta, const int* __restrict__ Tp,
    u16* __restrict__ rate, float* __restrict__ colsum)
{
    // [slot 2][buf 4: Ah,Al,Bh,Bl][8192 u16 = 256 rows x 32 k] = 128 KiB
    __shared__ __align__(16) u16 lds[2 * 4 * 8192];

    const int t = threadIdx.x;
    const int l = t & 63, w = t >> 6;           // 8 waves
    const int wm = w >> 2, wn = w & 3;          // 2 (M) x 4 (N)

    // bijective XCD swizzle: 32 consecutive ids (2 bm-rows) per XCD
    const int flat = blockIdx.y * gridDim.x + blockIdx.x;      // 0..255
    const int swz  = (flat & 7) * 32 + (flat >> 3);
    const int bm = (swz >> 4) * 256, bn = (swz & 15) * 256;

    // staging addressing (per-thread constant); LDS dest linear, source k
    // pre-swizzled (involution with read-side XOR)
    const int srow = t >> 2;                               // 0..127
    const int koff = (((t & 3) ^ ((t >> 3) & 3)) << 3);
    const size_t gA0 = (size_t)(bm + srow) * DDIM + koff;
    const size_t gA1 = (size_t)(bm + 128 + srow) * DDIM + koff;
    const size_t gB0 = (size_t)(bn + srow) * DDIM + koff;
    const size_t gB1 = (size_t)(bn + 128 + srow) * DDIM + koff;
    const int dst = t * 8;

#define ST8(slot, step) do {                                                  \
    const int k0_ = (step) << 5;                                              \
    u16* Lb_ = &lds[(slot) * 32768];                                          \
    gload_lds16(xh + gA0 + k0_, Lb_ + 0 * 8192 + dst);                        \
    gload_lds16(xh + gA1 + k0_, Lb_ + 0 * 8192 + 4096 + dst);                 \
    gload_lds16(xl + gA0 + k0_, Lb_ + 1 * 8192 + dst);                        \
    gload_lds16(xl + gA1 + k0_, Lb_ + 1 * 8192 + 4096 + dst);                 \
    gload_lds16(wh + gB0 + k0_, Lb_ + 2 * 8192 + dst);                        \
    gload_lds16(wh + gB1 + k0_, Lb_ + 2 * 8192 + 4096 + dst);                 \
    gload_lds16(wl + gB0 + k0_, Lb_ + 3 * 8192 + dst);                        \
    gload_lds16(wl + gB1 + k0_, Lb_ + 3 * 8192 + 4096 + dst);                 \
} while (0)

    // fragment read addressing (32x32x16: row = lane&31, k = (lane>>5)*8+j)
    const int lr32 = l & 31;
    const int kq   = l >> 5;
    const int sx   = (lr32 >> 1) & 3;             // swizzle key (row>>1)&3
    const int ps0  = ((0 * 2 + kq) ^ sx) << 3;    // k-half 0 phys slot (u16)
    const int ps1  = ((1 * 2 + kq) ^ sx) << 3;    // k-half 1

    f32x16 acc[4][2];
#pragma unroll
    for (int m = 0; m < 4; ++m)
#pragma unroll
        for (int n = 0; n < 2; ++n) acc[m][n] = (f32x16)0.0f;

    // prologue: stage tile 0 into slot 0
    ST8(0, 0);
    asm volatile("s_waitcnt vmcnt(0)" ::: "memory");
    __builtin_amdgcn_s_barrier();

    const int NT = DDIM / 32;   // 32
#pragma unroll 1
    for (int ts = 0; ts < NT; ++ts) {
        const int sb = (ts & 1) * 32768;
        bf16x8 bh[2][2], bl[2][2], ah[2][2], al[2][2];

        // ---- phase 0: read all B + A(m0,m1); stage next tile ----
#pragma unroll
        for (int n = 0; n < 2; ++n) {
            const int ro = sb + (wn * 64 + n * 32 + lr32) * 32;
            bh[n][0] = *(const bf16x8*)&lds[ro + 2 * 8192 + ps0];
            bh[n][1] = *(const bf16x8*)&lds[ro + 2 * 8192 + ps1];
            bl[n][0] = *(const bf16x8*)&lds[ro + 3 * 8192 + ps0];
            bl[n][1] = *(const bf16x8*)&lds[ro + 3 * 8192 + ps1];
        }
#pragma unroll
        for (int mi = 0; mi < 2; ++mi) {
            const int ro = sb + (wm * 128 + mi * 32 + lr32) * 32;
            ah[mi][0] = *(const bf16x8*)&lds[ro + ps0];
            ah[mi][1] = *(const bf16x8*)&lds[ro + ps1];
            al[mi][0] = *(const bf16x8*)&lds[ro + 8192 + ps0];
            al[mi][1] = *(const bf16x8*)&lds[ro + 8192 + ps1];
        }
        if (ts + 1 < NT) ST8((ts + 1) & 1, ts + 1);
        __builtin_amdgcn_s_barrier();
        asm volatile("s_waitcnt lgkmcnt(0)" ::: "memory");
        __builtin_amdgcn_sched_barrier(0);
        __builtin_amdgcn_s_setprio(1);
#pragma unroll
        for (int mi = 0; mi < 2; ++mi)
#pragma unroll
            for (int n = 0; n < 2; ++n) {
                f32x16 c = acc[mi][n];
                c = MFMA32(ah[mi][0], bh[n][0], c);
                c = MFMA32(ah[mi][0], bl[n][0], c);
                c = MFMA32(al[mi][0], bh[n][0], c);
                c = MFMA32(ah[mi][1], bh[n][1], c);
                c = MFMA32(ah[mi][1], bl[n][1], c);
                c = MFMA32(al[mi][1], bh[n][1], c);
                acc[mi][n] = c;
            }
        __builtin_amdgcn_s_setprio(0);

        // ---- phase 1: read A(m2,m3), compute ----
#pragma unroll
        for (int mi = 0; mi < 2; ++mi) {
            const int ro = sb + (wm * 128 + (2 + mi) * 32 + lr32) * 32;
            ah[mi][0] = *(const bf16x8*)&lds[ro + ps0];
            ah[mi][1] = *(const bf16x8*)&lds[ro + ps1];
            al[mi][0] = *(const bf16x8*)&lds[ro + 8192 + ps0];
            al[mi][1] = *(const bf16x8*)&lds[ro + 8192 + ps1];
        }
        __builtin_amdgcn_s_barrier();
        asm volatile("s_waitcnt lgkmcnt(0)" ::: "memory");
        __builtin_amdgcn_sched_barrier(0);
        __builtin_amdgcn_s_setprio(1);
#pragma unroll
        for (int mi = 0; mi < 2; ++mi)
#pragma unroll
            for (int n = 0; n < 2; ++n) {
                f32x16 c = acc[2 + mi][n];
                c = MFMA32(ah[mi][0], bh[n][0], c);
                c = MFMA32(ah[mi][0], bl[n][0], c);
                c = MFMA32(al[mi][0], bh[n][0], c);
                c = MFMA32(ah[mi][1], bh[n][1], c);
                c = MFMA32(ah[mi][1], bl[n][1], c);
                c = MFMA32(al[mi][1], bh[n][1], c);
                acc[2 + mi][n] = c;
            }
        __builtin_amdgcn_s_setprio(0);

        if (ts < NT - 1) {
            asm volatile("s_waitcnt vmcnt(0)" ::: "memory");  // next tile landed
            __builtin_amdgcn_s_barrier();
        }
    }
#undef ST8

    // ---- epilogue: LIF recurrence, rate write (64B rows), fused column sums
    const int T = Tp[0];
    const float invT = 1.0f / (float)T;
#pragma unroll
    for (int n = 0; n < 2; ++n) {
        const int f = bn + wn * 64 + n * 32 + lr32;
        const float bet = beta[f];
        float colacc = 0.f;
#pragma unroll
        for (int m = 0; m < 4; ++m) {
            const int rbase = bm + wm * 128 + m * 32 + kq * 4;
#pragma unroll
            for (int reg = 0; reg < 16; ++reg) {
                const int row = rbase + (reg & 3) + 8 * (reg >> 2);
                const float h = acc[m][n][reg];
                float v = 0.f, ss = 0.f;
                if (T == 8) {
#pragma unroll
                    for (int tt = 0; tt < 8; ++tt) {
                        v = fmaf(bet, v, h);
                        float s = (v > 1.0f) ? 1.0f : 0.0f;
                        ss += s; v -= s;
                    }
                } else {
                    for (int tt = 0; tt < T; ++tt) {
                        v = fmaf(bet, v, h);
                        float s = (v > 1.0f) ? 1.0f : 0.0f;
                        ss += s; v -= s;
                    }
                }
                const float rv = ss * invT;                 // exact k/8
                rate[(size_t)row * FDIM + f] = f32_to_bf16_rn(rv);
                colacc += rv;
            }
        }
        colacc += __shfl_xor(colacc, 32, 64);    // lanes l, l+32 share f
        if (l < 32) atomicAdd(&colsum[f], colacc);
    }
}

// ---- down-GEMM: 128x128 tile, BK=64, 8 waves (2Mx4N), 32x32x16, 3-slot
//      counted-vmcnt pipeline, swizzled LDS. out = rate @ wd^T (fp32) ----
__global__ __launch_bounds__(512, 2) void down_mfma(
    const u16* __restrict__ rate, const u16* __restrict__ wd,
    float* __restrict__ out)
{
    // slot = A[128][64] + B[128][64] u16 = 32 KiB; 3 slots = 96 KiB
    __shared__ __align__(16) u16 lds[3 * 2 * 8192];

    const int t = threadIdx.x;
    const int l = t & 63, w = t >> 6;
    const int wm = w >> 2, wn = w & 3;          // 2 (M) x 4 (N); wave tile 64x32

    const int flat = blockIdx.y * gridDim.x + blockIdx.x;   // 0..255
    const int swz  = (flat & 7) * 32 + (flat >> 3);
    const int bm = (swz >> 3) * 128;            // 0..31 -> rows
    const int bn = (swz & 7) * 128;             // 0..7  -> d-cols

    // staging: row = t>>3 (0..63), 8 slots of 16B per 128B row; key = row&7
    const int srow = t >> 3;
    const int koff = (((t & 7) ^ ((t >> 3) & 7)) << 3);
    const size_t gA0 = (size_t)(bm + srow) * FDIM + koff;
    const size_t gA1 = gA0 + (size_t)64 * FDIM;
    const size_t gB0 = (size_t)(bn + srow) * FDIM + koff;
    const size_t gB1 = gB0 + (size_t)64 * FDIM;
    const int dst = t * 8;

#define STD(slot, step) do {                                                  \
    const int k0_ = (step) << 6;                                              \
    u16* Lb_ = &lds[(slot) * 16384];                                          \
    gload_lds16(rate + gA0 + k0_, Lb_ + dst);                                 \
    gload_lds16(rate + gA1 + k0_, Lb_ + 4096 + dst);                          \
    gload_lds16(wd + gB0 + k0_, Lb_ + 8192 + dst);                            \
    gload_lds16(wd + gB1 + k0_, Lb_ + 12288 + dst);                           \
} while (0)

    const int lr32 = l & 31;
    const int kq   = l >> 5;
    const int sx8  = lr32 & 7;                  // swizzle key (row&7)

    f32x16 acc[2];
    acc[0] = (f32x16)0.0f; acc[1] = (f32x16)0.0f;

    // prologue: stage tiles 0,1
    STD(0, 0);
    STD(1, 1);
    asm volatile("s_waitcnt vmcnt(4)" ::: "memory");
    __builtin_amdgcn_s_barrier();

    const int NT = FDIM / 64;   // 64
#pragma unroll 1
    for (int ts = 0; ts < NT; ++ts) {
        const int sb = (ts % 3) * 16384;
        bf16x8 a[2][4], b[4];
#pragma unroll
        for (int h = 0; h < 4; ++h) {
            const int ps = (((h * 2 + kq) ^ sx8) << 3);
#pragma unroll
            for (int mi = 0; mi < 2; ++mi)
                a[mi][h] = *(const bf16x8*)&lds[sb + (wm * 64 + mi * 32 + lr32) * 64 + ps];
            b[h] = *(const bf16x8*)&lds[sb + 8192 + (wn * 32 + lr32) * 64 + ps];
        }
        if (ts + 2 < NT) STD((ts + 2) % 3, ts + 2);
        __builtin_amdgcn_s_barrier();
        asm volatile("s_waitcnt lgkmcnt(0)" ::: "memory");
        __builtin_amdgcn_sched_barrier(0);
        __builtin_amdgcn_s_setprio(1);
#pragma unroll
        for (int h = 0; h < 4; ++h) {
            acc[0] = MFMA32(a[0][h], b[h], acc[0]);
            acc[1] = MFMA32(a[1][h], b[h], acc[1]);
        }
        __builtin_amdgcn_s_setprio(0);
        if (ts < NT - 1) {
            if (ts < NT - 2) { asm volatile("s_waitcnt vmcnt(4)" ::: "memory"); }
            else             { asm volatile("s_waitcnt vmcnt(0)" ::: "memory"); }
            __builtin_amdgcn_s_barrier();
        }
    }
#undef STD

    const int col = bn + wn * 32 + lr32;
#pragma unroll
    for (int mi = 0; mi < 2; ++mi) {
        const int rbase = bm + wm * 64 + mi * 32 + kq * 4;
#pragma unroll
        for (int reg = 0; reg < 16; ++reg) {
            const int row = rbase + (reg & 3) + 8 * (reg >> 2);
            out[(size_t)row * DDIM + col] = acc[mi][reg];
        }
    }
}

// ---- rate_per_unit helpers ----
__global__ void zero_colsum(float* __restrict__ colsum) {
    colsum[blockIdx.x * 256 + threadIdx.x] = 0.f;
}
__global__ void finalize_rpu(const float* __restrict__ colsum, float* __restrict__ out_rpu) {
    const int f = blockIdx.x * 256 + threadIdx.x;
    out_rpu[f] = colsum[f] * (1.0f / (float)N_ROWS);
}

extern "C" void kernel_launch(void* const* d_in, const int* in_sizes, int n_in,
                              void* d_out, int out_size, void* d_ws, size_t ws_size,
                              hipStream_t stream) {
    const float* x     = (const float*)d_in[0];
    const float* wup   = (const float*)d_in[1];
    const float* wdown = (const float*)d_in[2];
    const float* beta  = (const float*)d_in[3];
    const int*   Tp    = (const int*)d_in[4];

    float* out     = (float*)d_out;
    float* out_rpu = out + (size_t)N_ROWS * DDIM;

    char* ws = (char*)d_ws;
    u16* rate = (u16*)ws;                                   // 33,554,432 B
    u16* xh   = (u16*)(ws + 33554432);
    u16* xl   = (u16*)(ws + 33554432 + 8388608);
    u16* wuph = (u16*)(ws + 33554432 + 2 * 8388608);
    u16* wupl = (u16*)(ws + 33554432 + 3 * 8388608);
    float* colsum = (float*)(ws + 33554432 + 4 * 8388608);
    u16* wdh  = xh;   // reuse xh region after up_mfma consumed it

    const int n4 = (N_ROWS * DDIM) / 4;

    split_kernel<<<2048, 256, 0, stream>>>(x, xh, xl, n4);
    split_kernel<<<2048, 256, 0, stream>>>(wup, wuph, wupl, n4);
    zero_colsum<<<FDIM / 256, 256, 0, stream>>>(colsum);

    up_mfma<<<dim3(FDIM / 256, N_ROWS / 256), 512, 0, stream>>>(
        xh, xl, wuph, wupl, beta, Tp, rate, colsum);

    split_kernel<<<2048, 256, 0, stream>>>(wdown, wdh, nullptr, n4);
    finalize_rpu<<<FDIM / 256, 256, 0, stream>>>(colsum, out_rpu);

    down_mfma<<<dim3(DDIM / 128, N_ROWS / 128), 512, 0, stream>>>(rate, wdh, out);
}

// Round 6
// 177.145 us; speedup vs baseline: 5.6610x; 1.0642x over previous
//
#include <hip/hip_runtime.h>

// Dims fixed by setup_inputs: B=2, S=2048, D=1024, F=4096, T=8
#define N_ROWS 4096
#define DDIM   1024
#define FDIM   4096

typedef unsigned short u16;
typedef __attribute__((ext_vector_type(8))) short bf16x8;
typedef __attribute__((ext_vector_type(4))) float f32x4;

#define MFMA(a, b, c) __builtin_amdgcn_mfma_f32_16x16x32_bf16((a), (b), (c), 0, 0, 0)

static __device__ __forceinline__ float bf16bits_to_f32(unsigned short u) {
    return __uint_as_float(((unsigned)u) << 16);
}
static __device__ __forceinline__ unsigned short f32_to_bf16_rn(float f) {
    unsigned u = __float_as_uint(f);
    unsigned r = 0x7fffu + ((u >> 16) & 1u);
    return (unsigned short)((u + r) >> 16);
}
static __device__ __forceinline__ void gload_lds16(const u16* g, u16* l) {
    __builtin_amdgcn_global_load_lds((const __attribute__((address_space(1))) unsigned*)g,
                                     (__attribute__((address_space(3))) unsigned*)l, 16, 0, 0);
}

// ---- split fp32 -> bf16 hi (+ optional lo residual) ----
__global__ __launch_bounds__(256) void split_kernel(
    const float* __restrict__ in, u16* __restrict__ hi,
    u16* __restrict__ lo, int n4)
{
    int i = blockIdx.x * 256 + threadIdx.x;
    const int stride = gridDim.x * 256;
    for (; i < n4; i += stride) {
        float4 v = ((const float4*)in)[i];
        ushort4 h;
        h.x = f32_to_bf16_rn(v.x); h.y = f32_to_bf16_rn(v.y);
        h.z = f32_to_bf16_rn(v.z); h.w = f32_to_bf16_rn(v.w);
        ((ushort4*)hi)[i] = h;
        if (lo) {
            ushort4 l;
            l.x = f32_to_bf16_rn(v.x - bf16bits_to_f32(h.x));
            l.y = f32_to_bf16_rn(v.y - bf16bits_to_f32(h.y));
            l.z = f32_to_bf16_rn(v.z - bf16bits_to_f32(h.z));
            l.w = f32_to_bf16_rn(v.w - bf16bits_to_f32(h.w));
            ((ushort4*)lo)[i] = l;
        }
    }
}

// ---- up-GEMM: 128x256 tile, BK=32, 8 waves (2Mx4N, wave-tile 64x64),
//      16x16x32 MFMA, 3-slot counted-vmcnt rotation (no mid-loop drains),
//      0-conflict XOR LDS addressing (R4-proven), split-bf16 (3 products),
//      fused LIF + column-sum epilogue. ----
__global__ __launch_bounds__(512, 1) void up_mfma(
    const u16* __restrict__ xh, const u16* __restrict__ xl,
    const u16* __restrict__ wh, const u16* __restrict__ wl,
    const float* __restrict__ beta, const int* __restrict__ Tp,
    u16* __restrict__ rate, float* __restrict__ colsum)
{
    // slot = xh[128][32] + xl[128][32] + wh[256][32] + wl[256][32] u16 = 48KB
    // 3 slots = 144 KiB
    __shared__ __align__(16) u16 lds[3 * 24576];

    const int t = threadIdx.x;
    const int l = t & 63, w = t >> 6;
    const int wm = w >> 2, wn = w & 3;          // 2 (M) x 4 (N), wave tile 64x64

    // bijective XCD swizzle: 512 blocks, 64 consecutive per XCD (shares B-panels)
    const int flat = blockIdx.y * gridDim.x + blockIdx.x;   // 0..511
    const int swz  = (flat & 7) * 64 + (flat >> 3);
    const int bm = (swz & 31) * 128;            // rows (x)
    const int bn = (swz >> 5) * 256;            // cols (f)

    // staging: dest linear t*16B; source k pre-swizzled (involution w/ read XOR)
    const int srow = t >> 2;                               // 0..127
    const int koff = (((t & 3) ^ ((t >> 3) & 3)) << 3);
    const size_t gX  = (size_t)(bm + srow) * DDIM + koff;
    const size_t gW0 = (size_t)(bn + srow) * DDIM + koff;
    const size_t gW1 = (size_t)(bn + 128 + srow) * DDIM + koff;
    const int dst = t * 8;

#define STG(slot, step) do {                                                  \
    const size_t k0_ = (size_t)(step) << 5;                                   \
    u16* Lb_ = &lds[(slot) * 24576];                                          \
    gload_lds16(xh + gX + k0_,  Lb_ + dst);                                   \
    gload_lds16(xl + gX + k0_,  Lb_ + 4096 + dst);                            \
    gload_lds16(wh + gW0 + k0_, Lb_ + 8192 + dst);                            \
    gload_lds16(wh + gW1 + k0_, Lb_ + 12288 + dst);                           \
    gload_lds16(wl + gW0 + k0_, Lb_ + 16384 + dst);                           \
    gload_lds16(wl + gW1 + k0_, Lb_ + 20480 + dst);                           \
} while (0)

    // fragment reads: psl proven 0-conflict in R4 (2-way max = free)
    const int lr = l & 15, lk = l >> 4;
    const int psl = ((lk ^ ((lr >> 1) & 3)) << 3);

    f32x4 acc[4][4];
#pragma unroll
    for (int m = 0; m < 4; ++m)
#pragma unroll
        for (int n = 0; n < 4; ++n) acc[m][n] = (f32x4){0.f, 0.f, 0.f, 0.f};

    // prologue: stage tiles 0,1 (12 loads in flight)
    STG(0, 0);
    STG(1, 1);

    const int NT = DDIM / 32;   // 32
#pragma unroll 1
    for (int ts = 0; ts < NT; ++ts) {
        // counted wait: tile ts's 6 loads landed (<=6 newest may pend)
        if (ts + 1 < NT) { asm volatile("s_waitcnt vmcnt(6)" ::: "memory"); }
        else             { asm volatile("s_waitcnt vmcnt(0)" ::: "memory"); }
        __builtin_amdgcn_s_barrier();

        // stage tile ts+2 into the slot last read at ts-1 (race-free)
        if (ts + 2 < NT) STG((ts + 2) % 3, ts + 2);

        const int sb = (ts % 3) * 24576;
        bf16x8 ah[4], al[4], bh[4], bl[4];
#pragma unroll
        for (int m = 0; m < 4; ++m) {
            const int ro = sb + (wm * 64 + m * 16 + lr) * 32 + psl;
            ah[m] = *(const bf16x8*)&lds[ro];
            al[m] = *(const bf16x8*)&lds[ro + 4096];
        }
#pragma unroll
        for (int n = 0; n < 4; ++n) {
            const int ro = sb + 8192 + (wn * 64 + n * 16 + lr) * 32 + psl;
            bh[n] = *(const bf16x8*)&lds[ro];
            bl[n] = *(const bf16x8*)&lds[ro + 8192];
        }
        __builtin_amdgcn_s_setprio(1);
#pragma unroll
        for (int m = 0; m < 4; ++m)
#pragma unroll
            for (int n = 0; n < 4; ++n) {
                f32x4 c = acc[m][n];
                c = MFMA(ah[m], bh[n], c);
                c = MFMA(ah[m], bl[n], c);
                c = MFMA(al[m], bh[n], c);
                acc[m][n] = c;
            }
        __builtin_amdgcn_s_setprio(0);
    }
#undef STG

    // ---- epilogue: LIF recurrence, rate write, fused column sums ----
    const int T = Tp[0];
    const float invT = 1.0f / (float)T;
#pragma unroll
    for (int n = 0; n < 4; ++n) {
        const int f = bn + wn * 64 + n * 16 + lr;
        const float bet = beta[f];
        float colacc = 0.f;
#pragma unroll
        for (int m = 0; m < 4; ++m) {
            const int row0 = bm + wm * 64 + m * 16 + lk * 4;
#pragma unroll
            for (int r = 0; r < 4; ++r) {
                const float h = acc[m][n][r];
                float v = 0.f, ss = 0.f;
                if (T == 8) {
#pragma unroll
                    for (int tt = 0; tt < 8; ++tt) {
                        v = fmaf(bet, v, h);
                        float s = (v > 1.0f) ? 1.0f : 0.0f;
                        ss += s; v -= s;
                    }
                } else {
                    for (int tt = 0; tt < T; ++tt) {
                        v = fmaf(bet, v, h);
                        float s = (v > 1.0f) ? 1.0f : 0.0f;
                        ss += s; v -= s;
                    }
                }
                const float rv = ss * invT;                 // exact k/8
                rate[(size_t)(row0 + r) * FDIM + f] = f32_to_bf16_rn(rv);
                colacc += rv;
            }
        }
        colacc += __shfl_xor(colacc, 16, 64);
        colacc += __shfl_xor(colacc, 32, 64);
        if (lk == 0) atomicAdd(&colsum[f], colacc);          // exact eighths
    }
}

// ---- down-GEMM: 128x128 tile, BK=64, 8 waves (2Mx4N, wave-tile 64x32),
//      16x16x32 MFMA, 3-slot counted-vmcnt rotation, 0-conflict XOR LDS.
//      out = rate(bf16) @ wd(bf16)^T, fp32 out ----
__global__ __launch_bounds__(512, 1) void down_mfma(
    const u16* __restrict__ rate, const u16* __restrict__ wd,
    float* __restrict__ out)
{
    // slot = A[128][64] + B[128][64] u16 = 32KB; 3 slots = 96KB
    __shared__ __align__(16) u16 lds[3 * 16384];

    const int t = threadIdx.x;
    const int l = t & 63, w = t >> 6;
    const int wm = w >> 2, wn = w & 3;          // wave tile 64x32

    const int flat = blockIdx.y * gridDim.x + blockIdx.x;   // 0..255
    const int swz  = (flat & 7) * 32 + (flat >> 3);
    const int bm = (swz & 31) * 128;            // rate rows
    const int bn = (swz >> 5) * 128;            // d cols

    // staging: 4 issues/thread/tile; key = row&7 involution
    const int srow = t >> 3;                               // 0..63
    const int koff = (((t & 7) ^ ((t >> 3) & 7)) << 3);
    const size_t gA0 = (size_t)(bm + srow) * FDIM + koff;
    const size_t gA1 = gA0 + (size_t)64 * FDIM;
    const size_t gB0 = (size_t)(bn + srow) * FDIM + koff;
    const size_t gB1 = gB0 + (size_t)64 * FDIM;
    const int dst = t * 8;

#define STD(slot, step) do {                                                  \
    const size_t k0_ = (size_t)(step) << 6;                                   \
    u16* Lb_ = &lds[(slot) * 16384];                                          \
    gload_lds16(rate + gA0 + k0_, Lb_ + dst);                                 \
    gload_lds16(rate + gA1 + k0_, Lb_ + 4096 + dst);                          \
    gload_lds16(wd + gB0 + k0_, Lb_ + 8192 + dst);                            \
    gload_lds16(wd + gB1 + k0_, Lb_ + 12288 + dst);                           \
} while (0)

    const int lr = l & 15, lk = l >> 4;
    // logical 16B slot L = ks*4 + lk within a 128B row; phys = L ^ (row&7)
    const int key = lr & 7;
    const int ps0 = ((0 * 4 + lk) ^ key) << 3;
    const int ps1 = ((1 * 4 + lk) ^ key) << 3;

    f32x4 acc[4][2];
#pragma unroll
    for (int m = 0; m < 4; ++m) {
        acc[m][0] = (f32x4){0.f, 0.f, 0.f, 0.f};
        acc[m][1] = (f32x4){0.f, 0.f, 0.f, 0.f};
    }

    STD(0, 0);
    STD(1, 1);

    const int NT = FDIM / 64;   // 64
#pragma unroll 1
    for (int ts = 0; ts < NT; ++ts) {
        if (ts + 1 < NT) { asm volatile("s_waitcnt vmcnt(4)" ::: "memory"); }
        else             { asm volatile("s_waitcnt vmcnt(0)" ::: "memory"); }
        __builtin_amdgcn_s_barrier();

        if (ts + 2 < NT) STD((ts + 2) % 3, ts + 2);

        const int sb = (ts % 3) * 16384;
        bf16x8 a[4][2], b[2][2];
#pragma unroll
        for (int m = 0; m < 4; ++m) {
            const int ro = sb + (wm * 64 + m * 16 + lr) * 64;
            a[m][0] = *(const bf16x8*)&lds[ro + ps0];
            a[m][1] = *(const bf16x8*)&lds[ro + ps1];
        }
#pragma unroll
        for (int n = 0; n < 2; ++n) {
            const int ro = sb + 8192 + (wn * 32 + n * 16 + lr) * 64;
            b[n][0] = *(const bf16x8*)&lds[ro + ps0];
            b[n][1] = *(const bf16x8*)&lds[ro + ps1];
        }
        __builtin_amdgcn_s_setprio(1);
#pragma unroll
        for (int m = 0; m < 4; ++m)
#pragma unroll
            for (int n = 0; n < 2; ++n) {
                f32x4 c = acc[m][n];
                c = MFMA(a[m][0], b[n][0], c);
                c = MFMA(a[m][1], b[n][1], c);
                acc[m][n] = c;
            }
        __builtin_amdgcn_s_setprio(0);
    }
#undef STD

#pragma unroll
    for (int n = 0; n < 2; ++n) {
        const int d = bn + wn * 32 + n * 16 + lr;
#pragma unroll
        for (int m = 0; m < 4; ++m) {
            const int row0 = bm + wm * 64 + m * 16 + lk * 4;
#pragma unroll
            for (int r = 0; r < 4; ++r)
                out[(size_t)(row0 + r) * DDIM + d] = acc[m][n][r];
        }
    }
}

// ---- rate_per_unit helpers ----
__global__ void zero_colsum(float* __restrict__ colsum) {
    colsum[blockIdx.x * 256 + threadIdx.x] = 0.f;
}
__global__ void finalize_rpu(const float* __restrict__ colsum, float* __restrict__ out_rpu) {
    const int f = blockIdx.x * 256 + threadIdx.x;
    out_rpu[f] = colsum[f] * (1.0f / (float)N_ROWS);
}

extern "C" void kernel_launch(void* const* d_in, const int* in_sizes, int n_in,
                              void* d_out, int out_size, void* d_ws, size_t ws_size,
                              hipStream_t stream) {
    const float* x     = (const float*)d_in[0];
    const float* wup   = (const float*)d_in[1];
    const float* wdown = (const float*)d_in[2];
    const float* beta  = (const float*)d_in[3];
    const int*   Tp    = (const int*)d_in[4];

    float* out     = (float*)d_out;
    float* out_rpu = out + (size_t)N_ROWS * DDIM;

    char* ws = (char*)d_ws;
    u16* rate = (u16*)ws;                                   // 33,554,432 B
    u16* xh   = (u16*)(ws + 33554432);
    u16* xl   = (u16*)(ws + 33554432 + 8388608);
    u16* wuph = (u16*)(ws + 33554432 + 2 * 8388608);
    u16* wupl = (u16*)(ws + 33554432 + 3 * 8388608);
    float* colsum = (float*)(ws + 33554432 + 4 * 8388608);
    u16* wdh  = xh;   // reuse xh region after up_mfma consumed it

    const int n4 = (N_ROWS * DDIM) / 4;

    split_kernel<<<2048, 256, 0, stream>>>(x, xh, xl, n4);
    split_kernel<<<2048, 256, 0, stream>>>(wup, wuph, wupl, n4);
    zero_colsum<<<FDIM / 256, 256, 0, stream>>>(colsum);

    up_mfma<<<dim3(FDIM / 256, N_ROWS / 128), 512, 0, stream>>>(
        xh, xl, wuph, wupl, beta, Tp, rate, colsum);

    split_kernel<<<2048, 256, 0, stream>>>(wdown, wdh, nullptr, n4);
    finalize_rpu<<<FDIM / 256, 256, 0, stream>>>(colsum, out_rpu);

    down_mfma<<<dim3(DDIM / 128, N_ROWS / 128), 512, 0, stream>>>(rate, wdh, out);
}

// Round 7
// 162.914 us; speedup vs baseline: 6.1555x; 1.0874x over previous
//
#include <hip/hip_runtime.h>

// Dims fixed by setup_inputs: B=2, S=2048, D=1024, F=4096, T=8
#define N_ROWS 4096
#define DDIM   1024
#define FDIM   4096

typedef unsigned short u16;
typedef __attribute__((ext_vector_type(8))) short bf16x8;
typedef __attribute__((ext_vector_type(4))) float f32x4;

#define MFMA(a, b, c) __builtin_amdgcn_mfma_f32_16x16x32_bf16((a), (b), (c), 0, 0, 0)

static __device__ __forceinline__ float bf16bits_to_f32(unsigned short u) {
    return __uint_as_float(((unsigned)u) << 16);
}
static __device__ __forceinline__ unsigned short f32_to_bf16_rn(float f) {
    unsigned u = __float_as_uint(f);
    unsigned r = 0x7fffu + ((u >> 16) & 1u);
    return (unsigned short)((u + r) >> 16);
}
static __device__ __forceinline__ void gload_lds16(const u16* g, u16* l) {
    __builtin_amdgcn_global_load_lds((const __attribute__((address_space(1))) unsigned*)g,
                                     (__attribute__((address_space(3))) unsigned*)l, 16, 0, 0);
}

// ---- split fp32 -> bf16 hi (+ optional lo residual) ----
__global__ __launch_bounds__(256) void split_kernel(
    const float* __restrict__ in, u16* __restrict__ hi,
    u16* __restrict__ lo, int n4)
{
    int i = blockIdx.x * 256 + threadIdx.x;
    const int stride = gridDim.x * 256;
    for (; i < n4; i += stride) {
        float4 v = ((const float4*)in)[i];
        ushort4 h;
        h.x = f32_to_bf16_rn(v.x); h.y = f32_to_bf16_rn(v.y);
        h.z = f32_to_bf16_rn(v.z); h.w = f32_to_bf16_rn(v.w);
        ((ushort4*)hi)[i] = h;
        if (lo) {
            ushort4 l;
            l.x = f32_to_bf16_rn(v.x - bf16bits_to_f32(h.x));
            l.y = f32_to_bf16_rn(v.y - bf16bits_to_f32(h.y));
            l.z = f32_to_bf16_rn(v.z - bf16bits_to_f32(h.z));
            l.w = f32_to_bf16_rn(v.w - bf16bits_to_f32(h.w));
            ((ushort4*)lo)[i] = l;
        }
    }
}

// ---- up-GEMM: 256x256 tile, BK=32, 8 waves (wave-tile 128x64), 16x16x32,
//      4-phase-per-K-tile interleave with counted vmcnt(8) (never 0 mid-loop),
//      2-slot dbuf, 0-conflict XOR LDS, split-bf16 (3 products),
//      fused LIF + column-sum epilogue. ----
__global__ __launch_bounds__(512, 2) void up_mfma(
    const u16* __restrict__ xh, const u16* __restrict__ xl,
    const u16* __restrict__ wh, const u16* __restrict__ wl,
    const float* __restrict__ beta, const int* __restrict__ Tp,
    u16* __restrict__ rate, float* __restrict__ colsum)
{
    // slot = Ah[256][32] Al Bh Bl u16 = 64KB; 2 slots = 128 KiB
    __shared__ __align__(16) u16 lds[2 * 32768];

    const int t = threadIdx.x;
    const int l = t & 63, w = t >> 6;
    const int wm = w >> 2, wn = w & 3;          // wave-tile 128(M) x 64(N)

    // per-XCD 4bm x 8bn rectangle (grid 16x16): fetch/XCD = 4+8 = 12MB
    const int flat = blockIdx.y * gridDim.x + blockIdx.x;   // 0..255
    const int xcd = flat & 7, wi = flat >> 3;                // wi 0..31
    const int bm = ((xcd & 3) * 4 + (wi & 3)) * 256;
    const int bn = ((xcd >> 2) * 8 + (wi >> 2)) * 256;

    // staging: dest linear t*16B; source k pre-swizzled (involution w/ read XOR)
    const int srow = t >> 2;                               // 0..127
    const int koff = (((t & 3) ^ ((t >> 3) & 3)) << 3);
    const size_t gX0 = (size_t)(bm + srow) * DDIM + koff;
    const size_t gX1 = gX0 + (size_t)128 * DDIM;
    const size_t gW0 = (size_t)(bn + srow) * DDIM + koff;
    const size_t gW1 = gW0 + (size_t)128 * DDIM;
    const int dst = t * 8;

#define STG_A(slot, step) do { const size_t k0_ = (size_t)(step) << 5;        \
    u16* Lb_ = &lds[(slot) * 32768];                                          \
    gload_lds16(xh + gX0 + k0_, Lb_ + dst);                                   \
    gload_lds16(xh + gX1 + k0_, Lb_ + 4096 + dst);                            \
    gload_lds16(xl + gX0 + k0_, Lb_ + 8192 + dst);                            \
    gload_lds16(xl + gX1 + k0_, Lb_ + 12288 + dst); } while (0)
#define STG_B(slot, step) do { const size_t k0_ = (size_t)(step) << 5;        \
    u16* Lb_ = &lds[(slot) * 32768 + 16384];                                  \
    gload_lds16(wh + gW0 + k0_, Lb_ + dst);                                   \
    gload_lds16(wh + gW1 + k0_, Lb_ + 4096 + dst);                            \
    gload_lds16(wl + gW0 + k0_, Lb_ + 8192 + dst);                            \
    gload_lds16(wl + gW1 + k0_, Lb_ + 12288 + dst); } while (0)

    // fragment reads (0-conflict XOR, proven R4/R6)
    const int lr = l & 15, lk = l >> 4;
    const int psl = ((lk ^ ((lr >> 1) & 3)) << 3);

    f32x4 acc[8][4];
#pragma unroll
    for (int m = 0; m < 8; ++m)
#pragma unroll
        for (int n = 0; n < 4; ++n) acc[m][n] = (f32x4){0.f, 0.f, 0.f, 0.f};

#define PHASE_TOP()                                              \
    __builtin_amdgcn_s_barrier();                                \
    asm volatile("s_waitcnt lgkmcnt(0)" ::: "memory");           \
    __builtin_amdgcn_sched_barrier(0);

    // prologue: stage tiles 0,1
    STG_A(0, 0); STG_B(0, 0);
    STG_A(1, 1); STG_B(1, 1);
    asm volatile("s_waitcnt vmcnt(8)" ::: "memory");   // tile 0 landed
    __builtin_amdgcn_s_barrier();

    const int NT = DDIM / 32;   // 32
#pragma unroll 1
    for (int ts = 0; ts < NT; ++ts) {
        const int s = ts & 1;
        const int sb = s * 32768;
        bf16x8 ah[4], al[4], ah2[4], al2[4], b0h[2], b0l[2], b1h[2], b1l[2];

        // ---- P0: read A(m0-3) + B(n0-1); MFMA quadrant (mh0, nh0) ----
#pragma unroll
        for (int mi = 0; mi < 4; ++mi) {
            const int ro = sb + (wm * 128 + mi * 16 + lr) * 32 + psl;
            ah[mi] = *(const bf16x8*)&lds[ro];
            al[mi] = *(const bf16x8*)&lds[ro + 8192];
        }
#pragma unroll
        for (int ni = 0; ni < 2; ++ni) {
            const int ro = sb + 16384 + (wn * 64 + ni * 16 + lr) * 32 + psl;
            b0h[ni] = *(const bf16x8*)&lds[ro];
            b0l[ni] = *(const bf16x8*)&lds[ro + 8192];
        }
        PHASE_TOP();
        __builtin_amdgcn_s_setprio(1);
#pragma unroll
        for (int mi = 0; mi < 4; ++mi)
#pragma unroll
            for (int ni = 0; ni < 2; ++ni) {
                f32x4 c = acc[mi][ni];
                c = MFMA(ah[mi], b0h[ni], c);
                c = MFMA(ah[mi], b0l[ni], c);
                c = MFMA(al[mi], b0h[ni], c);
                acc[mi][ni] = c;
            }
        __builtin_amdgcn_s_setprio(0);
        __builtin_amdgcn_s_barrier();

        // ---- P1: read B(n2-3); MFMA quadrant (mh0, nh1) ----
#pragma unroll
        for (int ni = 0; ni < 2; ++ni) {
            const int ro = sb + 16384 + (wn * 64 + (2 + ni) * 16 + lr) * 32 + psl;
            b1h[ni] = *(const bf16x8*)&lds[ro];
            b1l[ni] = *(const bf16x8*)&lds[ro + 8192];
        }
        PHASE_TOP();
        __builtin_amdgcn_s_setprio(1);
#pragma unroll
        for (int mi = 0; mi < 4; ++mi)
#pragma unroll
            for (int ni = 0; ni < 2; ++ni) {
                f32x4 c = acc[mi][2 + ni];
                c = MFMA(ah[mi], b1h[ni], c);
                c = MFMA(ah[mi], b1l[ni], c);
                c = MFMA(al[mi], b1h[ni], c);
                acc[mi][2 + ni] = c;
            }
        __builtin_amdgcn_s_setprio(0);
        __builtin_amdgcn_s_barrier();

        // ---- P2: read A(m4-7); stage B(ts+2) (B of slot s fully consumed
        //      after P1's joined lgkm0+barrier); MFMA quadrant (mh1, nh1) ----
#pragma unroll
        for (int mi = 0; mi < 4; ++mi) {
            const int ro = sb + (wm * 128 + (4 + mi) * 16 + lr) * 32 + psl;
            ah2[mi] = *(const bf16x8*)&lds[ro];
            al2[mi] = *(const bf16x8*)&lds[ro + 8192];
        }
        if (ts + 2 < NT) STG_B(s, ts + 2);
        PHASE_TOP();
        __builtin_amdgcn_s_setprio(1);
#pragma unroll
        for (int mi = 0; mi < 4; ++mi)
#pragma unroll
            for (int ni = 0; ni < 2; ++ni) {
                f32x4 c = acc[4 + mi][2 + ni];
                c = MFMA(ah2[mi], b1h[ni], c);
                c = MFMA(ah2[mi], b1l[ni], c);
                c = MFMA(al2[mi], b1h[ni], c);
                acc[4 + mi][2 + ni] = c;
            }
        __builtin_amdgcn_s_setprio(0);
        __builtin_amdgcn_s_barrier();

        // ---- P3: stage A(ts+2); MFMA quadrant (mh1, nh0) from registers ----
        if (ts + 2 < NT) STG_A(s, ts + 2);
        __builtin_amdgcn_s_barrier();
        __builtin_amdgcn_sched_barrier(0);
        __builtin_amdgcn_s_setprio(1);
#pragma unroll
        for (int mi = 0; mi < 4; ++mi)
#pragma unroll
            for (int ni = 0; ni < 2; ++ni) {
                f32x4 c = acc[4 + mi][ni];
                c = MFMA(ah2[mi], b0h[ni], c);
                c = MFMA(ah2[mi], b0l[ni], c);
                c = MFMA(al2[mi], b0h[ni], c);
                acc[4 + mi][ni] = c;
            }
        __builtin_amdgcn_s_setprio(0);
        // tile end: counted wait — next tile's 8 loads landed; <=8 (ts+2) pend
        if (ts + 2 < NT) {
            asm volatile("s_waitcnt vmcnt(8)" ::: "memory");
            __builtin_amdgcn_s_barrier();
        } else if (ts + 1 < NT) {
            asm volatile("s_waitcnt vmcnt(0)" ::: "memory");
            __builtin_amdgcn_s_barrier();
        }
    }
#undef STG_A
#undef STG_B
#undef PHASE_TOP

    // ---- epilogue: LIF recurrence, rate write, fused column sums ----
    const int T = Tp[0];
    const float invT = 1.0f / (float)T;
#pragma unroll
    for (int n = 0; n < 4; ++n) {
        const int f = bn + wn * 64 + n * 16 + lr;
        const float bet = beta[f];
        float colacc = 0.f;
#pragma unroll
        for (int m = 0; m < 8; ++m) {
            const int row0 = bm + wm * 128 + m * 16 + lk * 4;
#pragma unroll
            for (int r = 0; r < 4; ++r) {
                const float h = acc[m][n][r];
                float v = 0.f, ss = 0.f;
                if (T == 8) {
#pragma unroll
                    for (int tt = 0; tt < 8; ++tt) {
                        v = fmaf(bet, v, h);
                        float s = (v > 1.0f) ? 1.0f : 0.0f;
                        ss += s; v -= s;
                    }
                } else {
                    for (int tt = 0; tt < T; ++tt) {
                        v = fmaf(bet, v, h);
                        float s = (v > 1.0f) ? 1.0f : 0.0f;
                        ss += s; v -= s;
                    }
                }
                const float rv = ss * invT;                 // exact k/8
                rate[(size_t)(row0 + r) * FDIM + f] = f32_to_bf16_rn(rv);
                colacc += rv;
            }
        }
        colacc += __shfl_xor(colacc, 16, 64);
        colacc += __shfl_xor(colacc, 32, 64);
        if (lk == 0) atomicAdd(&colsum[f], colacc);          // exact eighths
    }
}

// ---- down-GEMM: 128x128 tile, BK=64, 8 waves (2Mx4N, wave-tile 64x32),
//      16x16x32 MFMA, 3-slot counted-vmcnt rotation, 0-conflict XOR LDS.
//      out = rate(bf16) @ wd(bf16)^T, fp32 out ----
__global__ __launch_bounds__(512, 1) void down_mfma(
    const u16* __restrict__ rate, const u16* __restrict__ wd,
    float* __restrict__ out)
{
    // slot = A[128][64] + B[128][64] u16 = 32KB; 3 slots = 96KB
    __shared__ __align__(16) u16 lds[3 * 16384];

    const int t = threadIdx.x;
    const int l = t & 63, w = t >> 6;
    const int wm = w >> 2, wn = w & 3;          // wave tile 64x32

    // per-XCD 8bm x 4bn rectangle (grid 32bm x 8bn): fetch/XCD = 8+4 = 12MB
    const int flat = blockIdx.y * gridDim.x + blockIdx.x;   // 0..255
    const int xcd = flat & 7, wi = flat >> 3;                // wi 0..31
    const int bm = ((xcd & 3) * 8 + (wi & 7)) * 128;
    const int bn = ((xcd >> 2) * 4 + (wi >> 3)) * 128;

    // staging: 4 issues/thread/tile; key = row&7 involution
    const int srow = t >> 3;                               // 0..63
    const int koff = (((t & 7) ^ ((t >> 3) & 7)) << 3);
    const size_t gA0 = (size_t)(bm + srow) * FDIM + koff;
    const size_t gA1 = gA0 + (size_t)64 * FDIM;
    const size_t gB0 = (size_t)(bn + srow) * FDIM + koff;
    const size_t gB1 = gB0 + (size_t)64 * FDIM;
    const int dst = t * 8;

#define STD(slot, step) do {                                                  \
    const size_t k0_ = (size_t)(step) << 6;                                   \
    u16* Lb_ = &lds[(slot) * 16384];                                          \
    gload_lds16(rate + gA0 + k0_, Lb_ + dst);                                 \
    gload_lds16(rate + gA1 + k0_, Lb_ + 4096 + dst);                          \
    gload_lds16(wd + gB0 + k0_, Lb_ + 8192 + dst);                            \
    gload_lds16(wd + gB1 + k0_, Lb_ + 12288 + dst);                           \
} while (0)

    const int lr = l & 15, lk = l >> 4;
    const int key = lr & 7;
    const int ps0 = ((0 * 4 + lk) ^ key) << 3;
    const int ps1 = ((1 * 4 + lk) ^ key) << 3;

    f32x4 acc[4][2];
#pragma unroll
    for (int m = 0; m < 4; ++m) {
        acc[m][0] = (f32x4){0.f, 0.f, 0.f, 0.f};
        acc[m][1] = (f32x4){0.f, 0.f, 0.f, 0.f};
    }

    STD(0, 0);
    STD(1, 1);

    const int NT = FDIM / 64;   // 64
#pragma unroll 1
    for (int ts = 0; ts < NT; ++ts) {
        if (ts + 1 < NT) { asm volatile("s_waitcnt vmcnt(4)" ::: "memory"); }
        else             { asm volatile("s_waitcnt vmcnt(0)" ::: "memory"); }
        __builtin_amdgcn_s_barrier();

        if (ts + 2 < NT) STD((ts + 2) % 3, ts + 2);

        const int sb = (ts % 3) * 16384;
        bf16x8 a[4][2], b[2][2];
#pragma unroll
        for (int m = 0; m < 4; ++m) {
            const int ro = sb + (wm * 64 + m * 16 + lr) * 64;
            a[m][0] = *(const bf16x8*)&lds[ro + ps0];
            a[m][1] = *(const bf16x8*)&lds[ro + ps1];
        }
#pragma unroll
        for (int n = 0; n < 2; ++n) {
            const int ro = sb + 8192 + (wn * 32 + n * 16 + lr) * 64;
            b[n][0] = *(const bf16x8*)&lds[ro + ps0];
            b[n][1] = *(const bf16x8*)&lds[ro + ps1];
        }
        __builtin_amdgcn_s_setprio(1);
#pragma unroll
        for (int m = 0; m < 4; ++m)
#pragma unroll
            for (int n = 0; n < 2; ++n) {
                f32x4 c = acc[m][n];
                c = MFMA(a[m][0], b[n][0], c);
                c = MFMA(a[m][1], b[n][1], c);
                acc[m][n] = c;
            }
        __builtin_amdgcn_s_setprio(0);
    }
#undef STD

#pragma unroll
    for (int n = 0; n < 2; ++n) {
        const int d = bn + wn * 32 + n * 16 + lr;
#pragma unroll
        for (int m = 0; m < 4; ++m) {
            const int row0 = bm + wm * 64 + m * 16 + lk * 4;
#pragma unroll
            for (int r = 0; r < 4; ++r)
                out[(size_t)(row0 + r) * DDIM + d] = acc[m][n][r];
        }
    }
}

// ---- rate_per_unit helpers ----
__global__ void zero_colsum(float* __restrict__ colsum) {
    colsum[blockIdx.x * 256 + threadIdx.x] = 0.f;
}
__global__ void finalize_rpu(const float* __restrict__ colsum, float* __restrict__ out_rpu) {
    const int f = blockIdx.x * 256 + threadIdx.x;
    out_rpu[f] = colsum[f] * (1.0f / (float)N_ROWS);
}

extern "C" void kernel_launch(void* const* d_in, const int* in_sizes, int n_in,
                              void* d_out, int out_size, void* d_ws, size_t ws_size,
                              hipStream_t stream) {
    const float* x     = (const float*)d_in[0];
    const float* wup   = (const float*)d_in[1];
    const float* wdown = (const float*)d_in[2];
    const float* beta  = (const float*)d_in[3];
    const int*   Tp    = (const int*)d_in[4];

    float* out     = (float*)d_out;
    float* out_rpu = out + (size_t)N_ROWS * DDIM;

    char* ws = (char*)d_ws;
    u16* rate = (u16*)ws;                                   // 33,554,432 B
    u16* xh   = (u16*)(ws + 33554432);
    u16* xl   = (u16*)(ws + 33554432 + 8388608);
    u16* wuph = (u16*)(ws + 33554432 + 2 * 8388608);
    u16* wupl = (u16*)(ws + 33554432 + 3 * 8388608);
    float* colsum = (float*)(ws + 33554432 + 4 * 8388608);
    u16* wdh  = xh;   // reuse xh region after up_mfma consumed it

    const int n4 = (N_ROWS * DDIM) / 4;

    split_kernel<<<2048, 256, 0, stream>>>(x, xh, xl, n4);
    split_kernel<<<2048, 256, 0, stream>>>(wup, wuph, wupl, n4);
    zero_colsum<<<FDIM / 256, 256, 0, stream>>>(colsum);

    up_mfma<<<dim3(16, 16), 512, 0, stream>>>(
        xh, xl, wuph, wupl, beta, Tp, rate, colsum);

    split_kernel<<<2048, 256, 0, stream>>>(wdown, wdh, nullptr, n4);
    finalize_rpu<<<FDIM / 256, 256, 0, stream>>>(colsum, out_rpu);

    down_mfma<<<dim3(DDIM / 128, N_ROWS / 128), 512, 0, stream>>>(rate, wdh, out);
}

// Round 8
// 147.329 us; speedup vs baseline: 6.8067x; 1.1058x over previous
//
#include <hip/hip_runtime.h>

// Dims fixed by setup_inputs: B=2, S=2048, D=1024, F=4096, T=8
#define N_ROWS 4096
#define DDIM   1024
#define FDIM   4096

typedef unsigned short u16;
typedef __attribute__((ext_vector_type(8))) _Float16 f16x8;
typedef __attribute__((ext_vector_type(4))) float f32x4;

#define MFMA16(a, b, c) __builtin_amdgcn_mfma_f32_16x16x32_f16((a), (b), (c), 0, 0, 0)

static __device__ __forceinline__ u16 f2h_bits(float f) {
    _Float16 h = (_Float16)f;
    return __builtin_bit_cast(u16, h);
}
static __device__ __forceinline__ void gload_lds16(const u16* g, u16* l) {
    __builtin_amdgcn_global_load_lds((const __attribute__((address_space(1))) unsigned*)g,
                                     (__attribute__((address_space(3))) unsigned*)l, 16, 0, 0);
}

// ---- fused prepass: x -> (xh, xl) fp16 ; wup -> wh fp16 ; wdown -> wd fp16 ;
//      zero colsum. One launch. ----
__global__ __launch_bounds__(256) void split_all(
    const float* __restrict__ x, const float* __restrict__ wup,
    const float* __restrict__ wdown,
    u16* __restrict__ xh, u16* __restrict__ xl,
    u16* __restrict__ wh, u16* __restrict__ wd, float* __restrict__ colsum)
{
    const int N4 = (N_ROWS * DDIM) / 4;   // 1,048,576 float4 per array (all three equal)
    int i = blockIdx.x * 256 + threadIdx.x;
    if (i < FDIM / 4) ((float4*)colsum)[i] = (float4){0.f, 0.f, 0.f, 0.f};
    const int stride = gridDim.x * 256;
    for (; i < 3 * N4; i += stride) {
        const int r = i >> 20;            // N4 == 2^20
        const int j = i & (N4 - 1);
        if (r == 0) {
            float4 v = ((const float4*)x)[j];
            ushort4 h, l;
            h.x = f2h_bits(v.x); h.y = f2h_bits(v.y);
            h.z = f2h_bits(v.z); h.w = f2h_bits(v.w);
            l.x = f2h_bits(v.x - (float)__builtin_bit_cast(_Float16, h.x));
            l.y = f2h_bits(v.y - (float)__builtin_bit_cast(_Float16, h.y));
            l.z = f2h_bits(v.z - (float)__builtin_bit_cast(_Float16, h.z));
            l.w = f2h_bits(v.w - (float)__builtin_bit_cast(_Float16, h.w));
            ((ushort4*)xh)[j] = h;
            ((ushort4*)xl)[j] = l;
        } else {
            const float4 v = (r == 1) ? ((const float4*)wup)[j] : ((const float4*)wdown)[j];
            ushort4 h;
            h.x = f2h_bits(v.x); h.y = f2h_bits(v.y);
            h.z = f2h_bits(v.z); h.w = f2h_bits(v.w);
            if (r == 1) ((ushort4*)wh)[j] = h; else ((ushort4*)wd)[j] = h;
        }
    }
}

// ---- up-GEMM: 256x256 tile, BK=32, 8 waves (4Mx2N, wave-tile 64x128),
//      fp16 16x16x32 MFMA, 2-product split (h = xh*wh + xl*wh = x*wh),
//      3-slot counted-vmcnt rotation (R6-proven, no mid-loop drains),
//      0-conflict XOR LDS, fused LIF + column-sum epilogue. ----
__global__ __launch_bounds__(512, 1) void up_mfma(
    const u16* __restrict__ xh, const u16* __restrict__ xl,
    const u16* __restrict__ wh,
    const float* __restrict__ beta, const int* __restrict__ Tp,
    u16* __restrict__ rate, float* __restrict__ colsum)
{
    // slot = Ah[256][32] + Al[256][32] + Bh[256][32] u16 = 48KB; 3 slots = 144KB
    __shared__ __align__(16) u16 lds[3 * 24576];

    const int t = threadIdx.x;
    const int l = t & 63, w = t >> 6;
    const int wm = w >> 1, wn = w & 1;          // wave-tile 64(M) x 128(N)

    // per-XCD 4bm x 8bn rectangle (grid 16x16): fetch/XCD ~ 12MB
    const int flat = blockIdx.y * gridDim.x + blockIdx.x;   // 0..255
    const int xcd = flat & 7, wi = flat >> 3;               // wi 0..31
    const int bm = ((xcd & 3) * 4 + (wi & 3)) * 256;
    const int bn = ((xcd >> 2) * 8 + (wi >> 2)) * 256;

    // staging: dest linear t*16B; source k pre-swizzled (involution w/ read XOR)
    const int srow = t >> 2;                                // 0..127
    const int koff = (((t & 3) ^ ((t >> 3) & 3)) << 3);
    const size_t gA0 = (size_t)(bm + srow) * DDIM + koff;
    const size_t gA1 = gA0 + (size_t)128 * DDIM;
    const size_t gB0 = (size_t)(bn + srow) * DDIM + koff;
    const size_t gB1 = gB0 + (size_t)128 * DDIM;
    const int dst = t * 8;

#define STG(slot, step) do {                                                  \
    const size_t k0_ = (size_t)(step) << 5;                                   \
    u16* Lb_ = &lds[(slot) * 24576];                                          \
    gload_lds16(xh + gA0 + k0_, Lb_ + dst);                                   \
    gload_lds16(xh + gA1 + k0_, Lb_ + 4096 + dst);                            \
    gload_lds16(xl + gA0 + k0_, Lb_ + 8192 + dst);                            \
    gload_lds16(xl + gA1 + k0_, Lb_ + 12288 + dst);                           \
    gload_lds16(wh + gB0 + k0_, Lb_ + 16384 + dst);                           \
    gload_lds16(wh + gB1 + k0_, Lb_ + 20480 + dst);                           \
} while (0)

    // fragment reads (0-conflict XOR, proven R4/R6/R7)
    const int lr = l & 15, lk = l >> 4;
    const int psl = ((lk ^ ((lr >> 1) & 3)) << 3);

    f32x4 acc[4][8];
#pragma unroll
    for (int m = 0; m < 4; ++m)
#pragma unroll
        for (int n = 0; n < 8; ++n) acc[m][n] = (f32x4){0.f, 0.f, 0.f, 0.f};

    // prologue: stage tiles 0,1 (12 loads in flight)
    STG(0, 0);
    STG(1, 1);

    const int NT = DDIM / 32;   // 32
#pragma unroll 1
    for (int ts = 0; ts < NT; ++ts) {
        // counted wait: tile ts's 6 loads landed (<=6 newest may pend)
        if (ts + 1 < NT) { asm volatile("s_waitcnt vmcnt(6)" ::: "memory"); }
        else             { asm volatile("s_waitcnt vmcnt(0)" ::: "memory"); }
        __builtin_amdgcn_s_barrier();

        // stage tile ts+2 into the slot last read at ts-1 (race-free: all
        // waves' ts-1 reads completed before this barrier)
        if (ts + 2 < NT) STG((ts + 2) % 3, ts + 2);

        const int sb = (ts % 3) * 24576;
        f16x8 ah[4], al[4], bh[8];
#pragma unroll
        for (int m = 0; m < 4; ++m) {
            const int ro = sb + (wm * 64 + m * 16 + lr) * 32 + psl;
            ah[m] = *(const f16x8*)&lds[ro];
            al[m] = *(const f16x8*)&lds[ro + 8192];
        }
#pragma unroll
        for (int n = 0; n < 8; ++n) {
            const int ro = sb + 16384 + (wn * 128 + n * 16 + lr) * 32 + psl;
            bh[n] = *(const f16x8*)&lds[ro];
        }
        __builtin_amdgcn_s_setprio(1);
#pragma unroll
        for (int m = 0; m < 4; ++m)
#pragma unroll
            for (int n = 0; n < 8; ++n) {
                f32x4 c = acc[m][n];
                c = MFMA16(ah[m], bh[n], c);
                c = MFMA16(al[m], bh[n], c);
                acc[m][n] = c;
            }
        __builtin_amdgcn_s_setprio(0);
    }
#undef STG

    // ---- epilogue: LIF recurrence, rate write (n-inner: full-line stores),
    //      fused column sums ----
    const int T = Tp[0];
    const float invT = 1.0f / (float)T;
    const int fbase = bn + wn * 128;
    float betav[8], colacc[8];
#pragma unroll
    for (int n = 0; n < 8; ++n) { betav[n] = beta[fbase + n * 16 + lr]; colacc[n] = 0.f; }

#pragma unroll
    for (int m = 0; m < 4; ++m) {
#pragma unroll
        for (int r = 0; r < 4; ++r) {
            const int row = bm + wm * 64 + m * 16 + lk * 4 + r;
            u16* rp = rate + (size_t)row * FDIM + fbase + lr;
#pragma unroll
            for (int n = 0; n < 8; ++n) {
                const float h = acc[m][n][r];
                const float bet = betav[n];
                float v = 0.f, ss = 0.f;
                if (T == 8) {
#pragma unroll
                    for (int tt = 0; tt < 8; ++tt) {
                        v = fmaf(bet, v, h);
                        float s = (v > 1.0f) ? 1.0f : 0.0f;
                        ss += s; v -= s;
                    }
                } else {
                    for (int tt = 0; tt < T; ++tt) {
                        v = fmaf(bet, v, h);
                        float s = (v > 1.0f) ? 1.0f : 0.0f;
                        ss += s; v -= s;
                    }
                }
                const float rv = ss * invT;                 // exact k/8 (fp16-exact)
                rp[n * 16] = f2h_bits(rv);
                colacc[n] += rv;
            }
        }
    }
#pragma unroll
    for (int n = 0; n < 8; ++n) {
        float ca = colacc[n];
        ca += __shfl_xor(ca, 16, 64);
        ca += __shfl_xor(ca, 32, 64);
        if (lk == 0) atomicAdd(&colsum[fbase + n * 16 + lr], ca);  // exact eighths
    }
}

// ---- down-GEMM: 128x128 tile, BK=64, 8 waves (2Mx4N, wave-tile 64x32),
//      fp16 16x16x32 MFMA, 3-slot counted-vmcnt rotation, 0-conflict XOR LDS.
//      out = rate(fp16) @ wd(fp16)^T, fp32 out ----
__global__ __launch_bounds__(512, 1) void down_mfma(
    const u16* __restrict__ rate, const u16* __restrict__ wd,
    float* __restrict__ out)
{
    // slot = A[128][64] + B[128][64] u16 = 32KB; 3 slots = 96KB
    __shared__ __align__(16) u16 lds[3 * 16384];

    const int t = threadIdx.x;
    const int l = t & 63, w = t >> 6;
    const int wm = w >> 2, wn = w & 3;          // wave tile 64x32

    // per-XCD 8bm x 4bn rectangle
    const int flat = blockIdx.y * gridDim.x + blockIdx.x;   // 0..255
    const int xcd = flat & 7, wi = flat >> 3;               // wi 0..31
    const int bm = ((xcd & 3) * 8 + (wi & 7)) * 128;
    const int bn = ((xcd >> 2) * 4 + (wi >> 3)) * 128;

    // staging: 4 issues/thread/tile; key = row&7 involution
    const int srow = t >> 3;                                // 0..63
    const int koff = (((t & 7) ^ ((t >> 3) & 7)) << 3);
    const size_t gA0 = (size_t)(bm + srow) * FDIM + koff;
    const size_t gA1 = gA0 + (size_t)64 * FDIM;
    const size_t gB0 = (size_t)(bn + srow) * FDIM + koff;
    const size_t gB1 = gB0 + (size_t)64 * FDIM;
    const int dst = t * 8;

#define STD(slot, step) do {                                                  \
    const size_t k0_ = (size_t)(step) << 6;                                   \
    u16* Lb_ = &lds[(slot) * 16384];                                          \
    gload_lds16(rate + gA0 + k0_, Lb_ + dst);                                 \
    gload_lds16(rate + gA1 + k0_, Lb_ + 4096 + dst);                          \
    gload_lds16(wd + gB0 + k0_, Lb_ + 8192 + dst);                            \
    gload_lds16(wd + gB1 + k0_, Lb_ + 12288 + dst);                           \
} while (0)

    const int lr = l & 15, lk = l >> 4;
    const int key = lr & 7;
    const int ps0 = ((0 * 4 + lk) ^ key) << 3;
    const int ps1 = ((1 * 4 + lk) ^ key) << 3;

    f32x4 acc[4][2];
#pragma unroll
    for (int m = 0; m < 4; ++m) {
        acc[m][0] = (f32x4){0.f, 0.f, 0.f, 0.f};
        acc[m][1] = (f32x4){0.f, 0.f, 0.f, 0.f};
    }

    STD(0, 0);
    STD(1, 1);

    const int NT = FDIM / 64;   // 64
#pragma unroll 1
    for (int ts = 0; ts < NT; ++ts) {
        if (ts + 1 < NT) { asm volatile("s_waitcnt vmcnt(4)" ::: "memory"); }
        else             { asm volatile("s_waitcnt vmcnt(0)" ::: "memory"); }
        __builtin_amdgcn_s_barrier();

        if (ts + 2 < NT) STD((ts + 2) % 3, ts + 2);

        const int sb = (ts % 3) * 16384;
        f16x8 a[4][2], b[2][2];
#pragma unroll
        for (int m = 0; m < 4; ++m) {
            const int ro = sb + (wm * 64 + m * 16 + lr) * 64;
            a[m][0] = *(const f16x8*)&lds[ro + ps0];
            a[m][1] = *(const f16x8*)&lds[ro + ps1];
        }
#pragma unroll
        for (int n = 0; n < 2; ++n) {
            const int ro = sb + 8192 + (wn * 32 + n * 16 + lr) * 64;
            b[n][0] = *(const f16x8*)&lds[ro + ps0];
            b[n][1] = *(const f16x8*)&lds[ro + ps1];
        }
        __builtin_amdgcn_s_setprio(1);
#pragma unroll
        for (int m = 0; m < 4; ++m)
#pragma unroll
            for (int n = 0; n < 2; ++n) {
                f32x4 c = acc[m][n];
                c = MFMA16(a[m][0], b[n][0], c);
                c = MFMA16(a[m][1], b[n][1], c);
                acc[m][n] = c;
            }
        __builtin_amdgcn_s_setprio(0);
    }
#undef STD

#pragma unroll
    for (int n = 0; n < 2; ++n) {
        const int d = bn + wn * 32 + n * 16 + lr;
#pragma unroll
        for (int m = 0; m < 4; ++m) {
            const int row0 = bm + wm * 64 + m * 16 + lk * 4;
#pragma unroll
            for (int r = 0; r < 4; ++r)
                out[(size_t)(row0 + r) * DDIM + d] = acc[m][n][r];
        }
    }
}

// ---- rate_per_unit ----
__global__ void finalize_rpu(const float* __restrict__ colsum, float* __restrict__ out_rpu) {
    const int f = blockIdx.x * 256 + threadIdx.x;
    out_rpu[f] = colsum[f] * (1.0f / (float)N_ROWS);
}

extern "C" void kernel_launch(void* const* d_in, const int* in_sizes, int n_in,
                              void* d_out, int out_size, void* d_ws, size_t ws_size,
                              hipStream_t stream) {
    const float* x     = (const float*)d_in[0];
    const float* wup   = (const float*)d_in[1];
    const float* wdown = (const float*)d_in[2];
    const float* beta  = (const float*)d_in[3];
    const int*   Tp    = (const int*)d_in[4];

    float* out     = (float*)d_out;
    float* out_rpu = out + (size_t)N_ROWS * DDIM;

    char* ws = (char*)d_ws;
    u16* rate = (u16*)ws;                                   // 33,554,432 B
    u16* xh   = (u16*)(ws + 33554432);                      //  8,388,608 B
    u16* xl   = (u16*)(ws + 33554432 + 8388608);
    u16* wh   = (u16*)(ws + 33554432 + 2 * 8388608);
    u16* wd   = (u16*)(ws + 33554432 + 3 * 8388608);
    float* colsum = (float*)(ws + 33554432 + 4 * 8388608);

    split_all<<<2048, 256, 0, stream>>>(x, wup, wdown, xh, xl, wh, wd, colsum);

    up_mfma<<<dim3(16, 16), 512, 0, stream>>>(xh, xl, wh, beta, Tp, rate, colsum);

    finalize_rpu<<<FDIM / 256, 256, 0, stream>>>(colsum, out_rpu);

    down_mfma<<<dim3(DDIM / 128, N_ROWS / 128), 512, 0, stream>>>(rate, wd, out);
}